// Round 11
// baseline (1572.245 us; speedup 1.0000x reference)
//
#include <hip/hip_runtime.h>

#define BB 32
#define LL 512
#define HH 1024
#define PRED 32
#define C8 8             // chunk length
#define NC8 (LL / C8)    // 64 chunks
#define LN_EPS 1e-5f

typedef short bf16x8 __attribute__((ext_vector_type(8)));
typedef short s16x4  __attribute__((ext_vector_type(4)));
typedef float f32x4  __attribute__((ext_vector_type(4)));

static __device__ __forceinline__ void split3(float x, short& h, short& m, short& l) {
    unsigned u = __float_as_uint(x);
    unsigned rh = (u + 0x7fffu + ((u >> 16) & 1u)) & 0xffff0000u;
    h = (short)(rh >> 16);
    float x1 = x - __uint_as_float(rh);
    unsigned u1 = __float_as_uint(x1);
    unsigned rm = (u1 + 0x7fffu + ((u1 >> 16) & 1u)) & 0xffff0000u;
    m = (short)(rm >> 16);
    float x2 = x1 - __uint_as_float(rm);
    unsigned u2 = __float_as_uint(x2);
    unsigned rl = (u2 + 0x7fffu + ((u2 >> 16) & 1u)) & 0xffff0000u;
    l = (short)(rl >> 16);
}

static __device__ __forceinline__ void split2(float x, short& h, short& m) {
    unsigned u = __float_as_uint(x);
    unsigned rh = (u + 0x7fffu + ((u >> 16) & 1u)) & 0xffff0000u;
    h = (short)(rh >> 16);
    float x1 = x - __uint_as_float(rh);
    unsigned u1 = __float_as_uint(x1);
    unsigned rm = (u1 + 0x7fffu + ((u1 >> 16) & 1u)) & 0xffff0000u;
    m = (short)(rm >> 16);
}

#define MFMA6(ACC, AH, AM, AL, BH, BM, BL) \
    ACC = __builtin_amdgcn_mfma_f32_16x16x32_bf16(AL, BH, ACC, 0, 0, 0); \
    ACC = __builtin_amdgcn_mfma_f32_16x16x32_bf16(AH, BL, ACC, 0, 0, 0); \
    ACC = __builtin_amdgcn_mfma_f32_16x16x32_bf16(AM, BM, ACC, 0, 0, 0); \
    ACC = __builtin_amdgcn_mfma_f32_16x16x32_bf16(AM, BH, ACC, 0, 0, 0); \
    ACC = __builtin_amdgcn_mfma_f32_16x16x32_bf16(AH, BM, ACC, 0, 0, 0); \
    ACC = __builtin_amdgcn_mfma_f32_16x16x32_bf16(AH, BH, ACC, 0, 0, 0);

// ---------------------------------------------------------------------------
__global__ __launch_bounds__(256) void transpose_k(const float* __restrict__ in,
                                                   float* __restrict__ out) {
    __shared__ float tile[32][33];
    int bx = blockIdx.x * 32, by = blockIdx.y * 32;
    int tx = threadIdx.x, ty = threadIdx.y;
    #pragma unroll
    for (int i = 0; i < 32; i += 8)
        tile[ty + i][tx] = in[(size_t)(by + ty + i) * HH + bx + tx];
    __syncthreads();
    #pragma unroll
    for (int i = 0; i < 32; i += 8)
        out[(size_t)(bx + ty + i) * HH + by + tx] = tile[tx][ty + i];
}

// ---------------------------------------------------------------------------
__global__ __launch_bounds__(256) void split_a(const float* __restrict__ src, long sb, long sc,
                                               short* __restrict__ dst, long dsb, long dsc,
                                               long ps) {
    int r = blockIdx.y;
    const float* s = src + (long)(r & 31) * sb + (long)(r >> 5) * sc + threadIdx.x * 4;
    short* d = dst + (long)(r & 31) * dsb + (long)(r >> 5) * dsc + threadIdx.x * 4;
    float4 v = *(const float4*)s;
    float xs[4] = {v.x, v.y, v.z, v.w};
    s16x4 vh, vm, vl;
    #pragma unroll
    for (int j = 0; j < 4; ++j) {
        short h, m, l;
        split3(xs[j], h, m, l);
        vh[j] = h; vm[j] = m; vl[j] = l;
    }
    *(s16x4*)(d) = vh;
    *(s16x4*)(d + ps) = vm;
    *(s16x4*)(d + 2 * ps) = vl;
}

// ---------------------------------------------------------------------------
__global__ __launch_bounds__(256) void split_t(const float* __restrict__ in,
                                               short* __restrict__ out) {
    const size_t HM = (size_t)HH * HH;
    __shared__ float tile[32][33];
    int n0 = blockIdx.x * 32, k0 = blockIdx.y * 32;
    int tx = threadIdx.x, ty = threadIdx.y;
    #pragma unroll
    for (int i = 0; i < 32; i += 8)
        tile[ty + i][tx] = in[(size_t)(k0 + ty + i) * HH + n0 + tx];
    __syncthreads();
    #pragma unroll
    for (int i = 0; i < 32; i += 8) {
        float v = tile[tx][ty + i];
        short h, m, l;
        split3(v, h, m, l);
        size_t o = (size_t)(n0 + ty + i) * HH + k0 + tx;
        out[o] = h; out[HM + o] = m; out[2 * HM + o] = l;
    }
}

// ---------------------------------------------------------------------------
__global__ __launch_bounds__(256) void tr_splits(const short* __restrict__ in,
                                                 short* __restrict__ out) {
    const size_t HM = (size_t)HH * HH;
    __shared__ short tile[32][33];
    int p = blockIdx.z;
    int k0 = blockIdx.x * 32, n0 = blockIdx.y * 32;
    int tx = threadIdx.x, ty = threadIdx.y;
    #pragma unroll
    for (int i = 0; i < 32; i += 8)
        tile[ty + i][tx] = in[p * HM + (size_t)(n0 + ty + i) * HH + k0 + tx];
    __syncthreads();
    #pragma unroll
    for (int i = 0; i < 32; i += 8)
        out[p * HM + (size_t)(k0 + ty + i) * HH + n0 + tx] = tile[tx][ty + i];
}

// ---------------------------------------------------------------------------
__global__ __launch_bounds__(256) void copy_splits(const short* __restrict__ src,
                                                   short* __restrict__ dst, long ps) {
    size_t off = (size_t)blockIdx.x * HH + threadIdx.x * 4;
    *(s16x4*)(dst + off)          = *(const s16x4*)(src + off);
    *(s16x4*)(dst + ps + off)     = *(const s16x4*)(src + ps + off);
    *(s16x4*)(dst + 2 * ps + off) = *(const s16x4*)(src + 2 * ps + off);
}

// ---------------------------------------------------------------------------
// gemm_mx: 128x64 tile (proven R7) — used by the 64-MiB fallback tier.
// ---------------------------------------------------------------------------
__global__ __launch_bounds__(256) void gemm_mx(const float* __restrict__ A,
                                               const short* __restrict__ SB,
                                               float* __restrict__ C) {
    const size_t HM = (size_t)HH * HH;
    __shared__ __align__(16) short As2[2][128][40];
    __shared__ __align__(16) short Bs2[2][64][40];
    const int tid = threadIdx.x;
    const int lane = tid & 63;
    const int w = tid >> 6;
    const int n0 = blockIdx.x * 64;
    const int m0 = blockIdx.y * 128;
    const int ar = tid >> 1;
    const int akc = (tid & 1) * 16;
    const float* Arow = A + (size_t)(m0 + ar) * HH + akc;
    const int bp = tid >> 7;
    const int bnr = tid & 63;
    const int bkh = ((tid >> 6) & 1) * 16;
    const short* Brow = SB + bp * HM + (size_t)(n0 + bnr) * HH + bkh;
    const int fr = lane & 15;
    const int fk = (lane >> 4) * 8;

    f32x4 acc[2][4] = {};

    float4 av0 = *(const float4*)(Arow);
    float4 av1 = *(const float4*)(Arow + 4);
    float4 av2 = *(const float4*)(Arow + 8);
    float4 av3 = *(const float4*)(Arow + 12);
    bf16x8 rb0 = *(const bf16x8*)(Brow);
    bf16x8 rb1 = *(const bf16x8*)(Brow + 8);

    for (int kt = 0; kt < HH; kt += 32) {
        float xs[16] = {av0.x, av0.y, av0.z, av0.w, av1.x, av1.y, av1.z, av1.w,
                        av2.x, av2.y, av2.z, av2.w, av3.x, av3.y, av3.z, av3.w};
        bf16x8 vh0, vm0, vh1, vm1;
        #pragma unroll
        for (int j = 0; j < 8; ++j) {
            short h, m;
            split2(xs[j], h, m);
            vh0[j] = h; vm0[j] = m;
            split2(xs[j + 8], h, m);
            vh1[j] = h; vm1[j] = m;
        }
        *(bf16x8*)&As2[0][ar][akc]     = vh0;
        *(bf16x8*)&As2[0][ar][akc + 8] = vh1;
        *(bf16x8*)&As2[1][ar][akc]     = vm0;
        *(bf16x8*)&As2[1][ar][akc + 8] = vm1;
        *(bf16x8*)&Bs2[bp][bnr][bkh]     = rb0;
        *(bf16x8*)&Bs2[bp][bnr][bkh + 8] = rb1;
        __syncthreads();
        if (kt + 32 < HH) {
            const float* An = Arow + kt + 32;
            av0 = *(const float4*)(An);
            av1 = *(const float4*)(An + 4);
            av2 = *(const float4*)(An + 8);
            av3 = *(const float4*)(An + 12);
            const short* Bn = Brow + kt + 32;
            rb0 = *(const bf16x8*)(Bn);
            rb1 = *(const bf16x8*)(Bn + 8);
        }
        bf16x8 ah[2], am[2];
        #pragma unroll
        for (int i = 0; i < 2; ++i) {
            ah[i] = *(const bf16x8*)&As2[0][w * 32 + i * 16 + fr][fk];
            am[i] = *(const bf16x8*)&As2[1][w * 32 + i * 16 + fr][fk];
        }
        #pragma unroll
        for (int j = 0; j < 4; ++j) {
            bf16x8 bh = *(const bf16x8*)&Bs2[0][j * 16 + fr][fk];
            bf16x8 bm = *(const bf16x8*)&Bs2[1][j * 16 + fr][fk];
            #pragma unroll
            for (int i = 0; i < 2; ++i) {
                f32x4 a = acc[i][j];
                a = __builtin_amdgcn_mfma_f32_16x16x32_bf16(am[i], bm, a, 0, 0, 0);
                a = __builtin_amdgcn_mfma_f32_16x16x32_bf16(am[i], bh, a, 0, 0, 0);
                a = __builtin_amdgcn_mfma_f32_16x16x32_bf16(ah[i], bm, a, 0, 0, 0);
                a = __builtin_amdgcn_mfma_f32_16x16x32_bf16(ah[i], bh, a, 0, 0, 0);
                acc[i][j] = a;
            }
        }
        __syncthreads();
    }
    const int orow = (lane >> 4) * 4;
    #pragma unroll
    for (int i = 0; i < 2; ++i)
        #pragma unroll
        for (int j = 0; j < 4; ++j) {
            int c = n0 + j * 16 + fr;
            #pragma unroll
            for (int reg = 0; reg < 4; ++reg) {
                int r = m0 + w * 32 + i * 16 + orow + reg;
                C[(size_t)r * HH + c] = acc[i][j][reg];
            }
        }
}

// ---------------------------------------------------------------------------
// gemm_mx2: 128x128 tile, 4 waves (wave tile 32x128), bf16 2x2 split.
// ---------------------------------------------------------------------------
__global__ __launch_bounds__(256) void gemm_mx2(const float* __restrict__ A,
                                                const short* __restrict__ SB,
                                                float* __restrict__ C) {
    const size_t HM = (size_t)HH * HH;
    __shared__ __align__(16) short As2[2][128][40];
    __shared__ __align__(16) short Bs2[2][128][40];
    const int tid = threadIdx.x;
    const int lane = tid & 63;
    const int w = tid >> 6;
    const int n0 = blockIdx.x * 128;
    const int m0 = blockIdx.y * 128;
    const int ar = tid >> 1;
    const int akc = (tid & 1) * 16;
    const float* Arow = A + (size_t)(m0 + ar) * HH + akc;
    const int bp = tid >> 7;                // plane 0/1
    const int bnr = tid & 127;              // n-row
    const short* Brow = SB + bp * HM + (size_t)(n0 + bnr) * HH;
    const int fr = lane & 15;
    const int fk = (lane >> 4) * 8;

    f32x4 acc[2][8] = {};

    float4 av0 = *(const float4*)(Arow);
    float4 av1 = *(const float4*)(Arow + 4);
    float4 av2 = *(const float4*)(Arow + 8);
    float4 av3 = *(const float4*)(Arow + 12);
    bf16x8 rb0 = *(const bf16x8*)(Brow);
    bf16x8 rb1 = *(const bf16x8*)(Brow + 8);
    bf16x8 rb2 = *(const bf16x8*)(Brow + 16);
    bf16x8 rb3 = *(const bf16x8*)(Brow + 24);

    for (int kt = 0; kt < HH; kt += 32) {
        float xs[16] = {av0.x, av0.y, av0.z, av0.w, av1.x, av1.y, av1.z, av1.w,
                        av2.x, av2.y, av2.z, av2.w, av3.x, av3.y, av3.z, av3.w};
        bf16x8 vh0, vm0, vh1, vm1;
        #pragma unroll
        for (int j = 0; j < 8; ++j) {
            short h, m;
            split2(xs[j], h, m);
            vh0[j] = h; vm0[j] = m;
            split2(xs[j + 8], h, m);
            vh1[j] = h; vm1[j] = m;
        }
        *(bf16x8*)&As2[0][ar][akc]     = vh0;
        *(bf16x8*)&As2[0][ar][akc + 8] = vh1;
        *(bf16x8*)&As2[1][ar][akc]     = vm0;
        *(bf16x8*)&As2[1][ar][akc + 8] = vm1;
        *(bf16x8*)&Bs2[bp][bnr][0]  = rb0;
        *(bf16x8*)&Bs2[bp][bnr][8]  = rb1;
        *(bf16x8*)&Bs2[bp][bnr][16] = rb2;
        *(bf16x8*)&Bs2[bp][bnr][24] = rb3;
        __syncthreads();
        if (kt + 32 < HH) {
            const float* An = Arow + kt + 32;
            av0 = *(const float4*)(An);
            av1 = *(const float4*)(An + 4);
            av2 = *(const float4*)(An + 8);
            av3 = *(const float4*)(An + 12);
            const short* Bn = Brow + kt + 32;
            rb0 = *(const bf16x8*)(Bn);
            rb1 = *(const bf16x8*)(Bn + 8);
            rb2 = *(const bf16x8*)(Bn + 16);
            rb3 = *(const bf16x8*)(Bn + 24);
        }
        bf16x8 ah[2], am[2];
        #pragma unroll
        for (int i = 0; i < 2; ++i) {
            ah[i] = *(const bf16x8*)&As2[0][w * 32 + i * 16 + fr][fk];
            am[i] = *(const bf16x8*)&As2[1][w * 32 + i * 16 + fr][fk];
        }
        #pragma unroll
        for (int j = 0; j < 8; ++j) {
            bf16x8 bh = *(const bf16x8*)&Bs2[0][j * 16 + fr][fk];
            bf16x8 bm = *(const bf16x8*)&Bs2[1][j * 16 + fr][fk];
            #pragma unroll
            for (int i = 0; i < 2; ++i) {
                f32x4 a = acc[i][j];
                a = __builtin_amdgcn_mfma_f32_16x16x32_bf16(am[i], bm, a, 0, 0, 0);
                a = __builtin_amdgcn_mfma_f32_16x16x32_bf16(am[i], bh, a, 0, 0, 0);
                a = __builtin_amdgcn_mfma_f32_16x16x32_bf16(ah[i], bm, a, 0, 0, 0);
                a = __builtin_amdgcn_mfma_f32_16x16x32_bf16(ah[i], bh, a, 0, 0, 0);
                acc[i][j] = a;
            }
        }
        __syncthreads();
    }
    const int orow = (lane >> 4) * 4;
    #pragma unroll
    for (int i = 0; i < 2; ++i)
        #pragma unroll
        for (int j = 0; j < 8; ++j) {
            int c = n0 + j * 16 + fr;
            #pragma unroll
            for (int reg = 0; reg < 4; ++reg) {
                int r = m0 + w * 32 + i * 16 + orow + reg;
                C[(size_t)r * HH + c] = acc[i][j][reg];
            }
        }
}

// ---------------------------------------------------------------------------
// step_g2: batched multi-descriptor bf16x6 MFMA GEMM, 128(M)x128(N) block,
// 4 waves (wave tile 32x128). Full per-group descriptors; group chosen by
// blockIdx.y >= g.ybeg (ascending). B plane stride fixed = H*H.
// ---------------------------------------------------------------------------
struct GDv {
    const short* A; const short* B; float* O; float* P; short* S;
    int sab, sac, psA, sob, soc, spb, spc, ssb, ssc, psS, add, nrows, ybeg;
};
struct GDv8 { GDv g[8]; };

__global__ __launch_bounds__(256) void step_g2(GDv8 dsc, int ng) {
    const size_t HM = (size_t)HH * HH;
    __shared__ __align__(16) short As[3][128][40];
    __shared__ __align__(16) short Bs[3][128][40];
    const int tid = threadIdx.x;
    const int lane = tid & 63;
    const int w = tid >> 6;              // wave owns rows w*32..w*32+31, all 128 cols
    const int yy = blockIdx.y;
    int gi = 0;
    for (int i = 1; i < ng; ++i)
        if (yy >= dsc.g[i].ybeg) gi = i;
    const GDv d = dsc.g[gi];
    const int n0 = blockIdx.x * 128;
    const int m0 = (yy - d.ybeg) * 128;
    // A staging: 128 rows x 32k x 3 planes; thread: row tid>>1, k-half (tid&1)*16
    const int ar = tid >> 1;
    const int akh = (tid & 1) * 16;
    const int agr = m0 + ar;
    const short* Arow = d.A + (long)(agr & 31) * d.sab + (long)(agr >> 5) * d.sac + akh;
    // B staging: same pattern on n
    const short* Brow = d.B + (size_t)(n0 + ar) * HH + akh;
    const int fr = lane & 15;
    const int fk = (lane >> 4) * 8;
    const long psA = d.psA;

    f32x4 acc[2][8] = {};

    bf16x8 ra[6], rb[6];
    #pragma unroll
    for (int p = 0; p < 3; ++p) {
        ra[2 * p]     = *(const bf16x8*)(Arow + p * psA);
        ra[2 * p + 1] = *(const bf16x8*)(Arow + p * psA + 8);
        rb[2 * p]     = *(const bf16x8*)(Brow + p * HM);
        rb[2 * p + 1] = *(const bf16x8*)(Brow + p * HM + 8);
    }
    for (int kt = 0; kt < HH; kt += 32) {
        #pragma unroll
        for (int p = 0; p < 3; ++p) {
            *(bf16x8*)&As[p][ar][akh]     = ra[2 * p];
            *(bf16x8*)&As[p][ar][akh + 8] = ra[2 * p + 1];
            *(bf16x8*)&Bs[p][ar][akh]     = rb[2 * p];
            *(bf16x8*)&Bs[p][ar][akh + 8] = rb[2 * p + 1];
        }
        __syncthreads();
        if (kt + 32 < HH) {
            #pragma unroll
            for (int p = 0; p < 3; ++p) {
                ra[2 * p]     = *(const bf16x8*)(Arow + p * psA + kt + 32);
                ra[2 * p + 1] = *(const bf16x8*)(Arow + p * psA + kt + 40);
                rb[2 * p]     = *(const bf16x8*)(Brow + p * HM + kt + 32);
                rb[2 * p + 1] = *(const bf16x8*)(Brow + p * HM + kt + 40);
            }
        }
        bf16x8 af[3][2];
        #pragma unroll
        for (int p = 0; p < 3; ++p)
            #pragma unroll
            for (int mf = 0; mf < 2; ++mf)
                af[p][mf] = *(const bf16x8*)&As[p][w * 32 + mf * 16 + fr][fk];
        #pragma unroll
        for (int nf = 0; nf < 8; ++nf) {
            bf16x8 b0 = *(const bf16x8*)&Bs[0][nf * 16 + fr][fk];
            bf16x8 b1 = *(const bf16x8*)&Bs[1][nf * 16 + fr][fk];
            bf16x8 b2 = *(const bf16x8*)&Bs[2][nf * 16 + fr][fk];
            MFMA6(acc[0][nf], af[0][0], af[1][0], af[2][0], b0, b1, b2)
            MFMA6(acc[1][nf], af[0][1], af[1][1], af[2][1], b0, b1, b2)
        }
        __syncthreads();
    }
    const int orow = (lane >> 4) * 4;
    #pragma unroll
    for (int mf = 0; mf < 2; ++mf)
        #pragma unroll
        for (int nf = 0; nf < 8; ++nf) {
            int c = n0 + nf * 16 + fr;
            #pragma unroll
            for (int reg = 0; reg < 4; ++reg) {
                int r = m0 + w * 32 + mf * 16 + orow + reg;
                if (r >= d.nrows) continue;
                long rb_ = (long)(r & 31), rc_ = (long)(r >> 5);
                float val = acc[mf][nf][reg];
                if (d.O) {
                    float* p = d.O + rb_ * d.sob + rc_ * d.soc + c;
                    if (d.add) val += *p;
                    *p = val;
                }
                if (d.P) {
                    float* q = d.P + rb_ * d.spb + rc_ * d.spc + c;
                    *q += val;
                }
                if (d.S) {
                    short h, m, l;
                    split3(val, h, m, l);
                    short* s = d.S + rb_ * d.ssb + rc_ * d.ssc + c;
                    s[0] = h; s[d.psS] = m; s[2 * (long)d.psS] = l;
                }
            }
        }
}

// ---------------------------------------------------------------------------
// step_p / step_p64 / step_p128: proven kernels kept for the 64-MiB fallback.
// ---------------------------------------------------------------------------
__global__ __launch_bounds__(128) void step_p(
    const short* __restrict__ SA, long sab, long sac, long psA,
    const short* __restrict__ SB,
    float* __restrict__ O, long sob, long soc, int add,
    float* __restrict__ P, long spb, long spc,
    short* __restrict__ S, long ssb, long ssc, long psS) {
    const size_t HM = (size_t)HH * HH;
    __shared__ __align__(16) short As[3][32][40];
    __shared__ __align__(16) short Bs[3][64][40];
    const int tid = threadIdx.x;
    const int lane = tid & 63;
    const int w = tid >> 6;
    const int n0 = blockIdx.x * 64;
    const int m0 = blockIdx.y * 32;
    const int ar = tid >> 2;
    const int akc = (tid & 3) * 8;
    const int agr = m0 + ar;
    const short* Arow = SA + (long)(agr & 31) * sab + (long)(agr >> 5) * sac + akc;
    const int bnr = tid & 63;
    const int bkh = (tid >> 6) * 16;
    const short* Brow = SB + (size_t)(n0 + bnr) * HH + bkh;
    const int fr = lane & 15;
    const int fk = (lane >> 4) * 8;
    f32x4 acc00 = 0, acc01 = 0, acc10 = 0, acc11 = 0;
    bf16x8 ra0 = *(const bf16x8*)(Arow);
    bf16x8 ra1 = *(const bf16x8*)(Arow + psA);
    bf16x8 ra2 = *(const bf16x8*)(Arow + 2 * psA);
    bf16x8 rb0 = *(const bf16x8*)(Brow);
    bf16x8 rb1 = *(const bf16x8*)(Brow + 8);
    bf16x8 rb2 = *(const bf16x8*)(Brow + HM);
    bf16x8 rb3 = *(const bf16x8*)(Brow + HM + 8);
    bf16x8 rb4 = *(const bf16x8*)(Brow + 2 * HM);
    bf16x8 rb5 = *(const bf16x8*)(Brow + 2 * HM + 8);
    for (int kt = 0; kt < HH; kt += 32) {
        *(bf16x8*)&As[0][ar][akc] = ra0;
        *(bf16x8*)&As[1][ar][akc] = ra1;
        *(bf16x8*)&As[2][ar][akc] = ra2;
        *(bf16x8*)&Bs[0][bnr][bkh] = rb0;
        *(bf16x8*)&Bs[0][bnr][bkh + 8] = rb1;
        *(bf16x8*)&Bs[1][bnr][bkh] = rb2;
        *(bf16x8*)&Bs[1][bnr][bkh + 8] = rb3;
        *(bf16x8*)&Bs[2][bnr][bkh] = rb4;
        *(bf16x8*)&Bs[2][bnr][bkh + 8] = rb5;
        __syncthreads();
        if (kt + 32 < HH) {
            const short* An = Arow + kt + 32;
            const short* Bn = Brow + kt + 32;
            ra0 = *(const bf16x8*)(An);
            ra1 = *(const bf16x8*)(An + psA);
            ra2 = *(const bf16x8*)(An + 2 * psA);
            rb0 = *(const bf16x8*)(Bn);
            rb1 = *(const bf16x8*)(Bn + 8);
            rb2 = *(const bf16x8*)(Bn + HM);
            rb3 = *(const bf16x8*)(Bn + HM + 8);
            rb4 = *(const bf16x8*)(Bn + 2 * HM);
            rb5 = *(const bf16x8*)(Bn + 2 * HM + 8);
        }
        bf16x8 a00 = *(const bf16x8*)&As[0][fr][fk];
        bf16x8 a01 = *(const bf16x8*)&As[0][16 + fr][fk];
        bf16x8 a10 = *(const bf16x8*)&As[1][fr][fk];
        bf16x8 a11 = *(const bf16x8*)&As[1][16 + fr][fk];
        bf16x8 a20 = *(const bf16x8*)&As[2][fr][fk];
        bf16x8 a21 = *(const bf16x8*)&As[2][16 + fr][fk];
        bf16x8 b00 = *(const bf16x8*)&Bs[0][w * 32 + fr][fk];
        bf16x8 b01 = *(const bf16x8*)&Bs[0][w * 32 + 16 + fr][fk];
        bf16x8 b10 = *(const bf16x8*)&Bs[1][w * 32 + fr][fk];
        bf16x8 b11 = *(const bf16x8*)&Bs[1][w * 32 + 16 + fr][fk];
        bf16x8 b20 = *(const bf16x8*)&Bs[2][w * 32 + fr][fk];
        bf16x8 b21 = *(const bf16x8*)&Bs[2][w * 32 + 16 + fr][fk];
        MFMA6(acc00, a00, a10, a20, b00, b10, b20)
        MFMA6(acc01, a00, a10, a20, b01, b11, b21)
        MFMA6(acc10, a01, a11, a21, b00, b10, b20)
        MFMA6(acc11, a01, a11, a21, b01, b11, b21)
        __syncthreads();
    }
    const int orow = (lane >> 4) * 4;
    #pragma unroll
    for (int mf = 0; mf < 2; ++mf) {
        #pragma unroll
        for (int nf = 0; nf < 2; ++nf) {
            f32x4 v = mf == 0 ? (nf == 0 ? acc00 : acc01) : (nf == 0 ? acc10 : acc11);
            int c = n0 + w * 32 + nf * 16 + fr;
            #pragma unroll
            for (int reg = 0; reg < 4; ++reg) {
                int r = m0 + mf * 16 + orow + reg;
                long rb = (long)(r & 31), rc = (long)(r >> 5);
                float val = v[reg];
                if (O) {
                    float* p = O + rb * sob + rc * soc + c;
                    if (add) val += *p;
                    *p = val;
                }
                if (P) { float* q = P + rb * spb + rc * spc + c; *q += val; }
                if (S) {
                    short h, m, l;
                    split3(val, h, m, l);
                    short* s = S + rb * ssb + rc * ssc + c;
                    s[0] = h; s[psS] = m; s[2 * psS] = l;
                }
            }
        }
    }
}

__global__ __launch_bounds__(256) void step_p64(
    const short* __restrict__ SA, long sab, long sac, long psA,
    const short* __restrict__ SB,
    float* __restrict__ O, long sob, long soc, int add,
    float* __restrict__ P, long spb, long spc,
    short* __restrict__ S, long ssb, long ssc, long psS,
    int nrows) {
    const size_t HM = (size_t)HH * HH;
    __shared__ __align__(16) short As[3][64][40];
    __shared__ __align__(16) short Bs[3][64][40];
    const int tid = threadIdx.x;
    const int lane = tid & 63;
    const int w = tid >> 6;
    const int wr = w & 1;
    const int wc = w >> 1;
    const int n0 = blockIdx.x * 64;
    const int m0 = blockIdx.y * 64;
    const int ar = tid >> 2;
    const int akc = (tid & 3) * 8;
    const int agr = m0 + ar;
    const short* Arow = SA + (long)(agr & 31) * sab + (long)(agr >> 5) * sac + akc;
    const short* Brow = SB + (size_t)(n0 + ar) * HH + akc;
    const int fr = lane & 15;
    const int fk = (lane >> 4) * 8;
    f32x4 acc00 = 0, acc01 = 0, acc10 = 0, acc11 = 0;
    bf16x8 ra0 = *(const bf16x8*)(Arow);
    bf16x8 ra1 = *(const bf16x8*)(Arow + psA);
    bf16x8 ra2 = *(const bf16x8*)(Arow + 2 * psA);
    bf16x8 rb0 = *(const bf16x8*)(Brow);
    bf16x8 rb1 = *(const bf16x8*)(Brow + HM);
    bf16x8 rb2 = *(const bf16x8*)(Brow + 2 * HM);
    for (int kt = 0; kt < HH; kt += 32) {
        *(bf16x8*)&As[0][ar][akc] = ra0;
        *(bf16x8*)&As[1][ar][akc] = ra1;
        *(bf16x8*)&As[2][ar][akc] = ra2;
        *(bf16x8*)&Bs[0][ar][akc] = rb0;
        *(bf16x8*)&Bs[1][ar][akc] = rb1;
        *(bf16x8*)&Bs[2][ar][akc] = rb2;
        __syncthreads();
        if (kt + 32 < HH) {
            const short* An = Arow + kt + 32;
            const short* Bn = Brow + kt + 32;
            ra0 = *(const bf16x8*)(An);
            ra1 = *(const bf16x8*)(An + psA);
            ra2 = *(const bf16x8*)(An + 2 * psA);
            rb0 = *(const bf16x8*)(Bn);
            rb1 = *(const bf16x8*)(Bn + HM);
            rb2 = *(const bf16x8*)(Bn + 2 * HM);
        }
        bf16x8 a00 = *(const bf16x8*)&As[0][wr * 32 + fr][fk];
        bf16x8 a01 = *(const bf16x8*)&As[0][wr * 32 + 16 + fr][fk];
        bf16x8 a10 = *(const bf16x8*)&As[1][wr * 32 + fr][fk];
        bf16x8 a11 = *(const bf16x8*)&As[1][wr * 32 + 16 + fr][fk];
        bf16x8 a20 = *(const bf16x8*)&As[2][wr * 32 + fr][fk];
        bf16x8 a21 = *(const bf16x8*)&As[2][wr * 32 + 16 + fr][fk];
        bf16x8 b00 = *(const bf16x8*)&Bs[0][wc * 32 + fr][fk];
        bf16x8 b01 = *(const bf16x8*)&Bs[0][wc * 32 + 16 + fr][fk];
        bf16x8 b10 = *(const bf16x8*)&Bs[1][wc * 32 + fr][fk];
        bf16x8 b11 = *(const bf16x8*)&Bs[1][wc * 32 + 16 + fr][fk];
        bf16x8 b20 = *(const bf16x8*)&Bs[2][wc * 32 + fr][fk];
        bf16x8 b21 = *(const bf16x8*)&Bs[2][wc * 32 + 16 + fr][fk];
        MFMA6(acc00, a00, a10, a20, b00, b10, b20)
        MFMA6(acc01, a00, a10, a20, b01, b11, b21)
        MFMA6(acc10, a01, a11, a21, b00, b10, b20)
        MFMA6(acc11, a01, a11, a21, b01, b11, b21)
        __syncthreads();
    }
    const int orow = (lane >> 4) * 4;
    #pragma unroll
    for (int mf = 0; mf < 2; ++mf) {
        #pragma unroll
        for (int nf = 0; nf < 2; ++nf) {
            f32x4 v = mf == 0 ? (nf == 0 ? acc00 : acc01) : (nf == 0 ? acc10 : acc11);
            int c = n0 + wc * 32 + nf * 16 + fr;
            #pragma unroll
            for (int reg = 0; reg < 4; ++reg) {
                int r = m0 + wr * 32 + mf * 16 + orow + reg;
                if (r >= nrows) continue;
                long rb = (long)(r & 31), rc = (long)(r >> 5);
                float val = v[reg];
                if (O) {
                    float* p = O + rb * sob + rc * soc + c;
                    if (add) val += *p;
                    *p = val;
                }
                if (P) { float* q = P + rb * spb + rc * spc + c; *q += val; }
                if (S) {
                    short h, m, l;
                    split3(val, h, m, l);
                    short* s = S + rb * ssb + rc * ssc + c;
                    s[0] = h; s[psS] = m; s[2 * psS] = l;
                }
            }
        }
    }
}

__global__ __launch_bounds__(512) void step_p128(
    const short* __restrict__ SA, long sab, long sac, long psA,
    const short* __restrict__ SB,
    float* __restrict__ O, long sob, long soc, int add,
    float* __restrict__ P, long spb, long spc,
    short* __restrict__ S, long ssb, long ssc, long psS,
    int nrows) {
    const size_t HM = (size_t)HH * HH;
    __shared__ __align__(16) short As[3][128][40];
    __shared__ __align__(16) short Bs[3][64][40];
    const int tid = threadIdx.x;
    const int lane = tid & 63;
    const int w = tid >> 6;
    const int wr = w & 3;
    const int wc = w >> 2;
    const int n0 = blockIdx.x * 64;
    const int m0 = blockIdx.y * 128;
    const int ar = tid >> 2;
    const int akc = (tid & 3) * 8;
    const int agr = m0 + ar;
    const short* Arow = SA + (long)(agr & 31) * sab + (long)(agr >> 5) * sac + akc;
    const bool bst = (tid < 384);
    const int bp = (tid >> 7) == 3 ? 2 : (tid >> 7);
    const int bt = tid & 127;
    const int bnr = bt >> 1;
    const int bkh = (bt & 1) * 16;
    const short* Brow = SB + (size_t)bp * HM + (size_t)(n0 + bnr) * HH + bkh;
    const int fr = lane & 15;
    const int fk = (lane >> 4) * 8;
    f32x4 acc00 = 0, acc01 = 0, acc10 = 0, acc11 = 0;
    bf16x8 ra0 = *(const bf16x8*)(Arow);
    bf16x8 ra1 = *(const bf16x8*)(Arow + psA);
    bf16x8 ra2 = *(const bf16x8*)(Arow + 2 * psA);
    bf16x8 rb0 = {}, rb1 = {};
    if (bst) { rb0 = *(const bf16x8*)(Brow); rb1 = *(const bf16x8*)(Brow + 8); }
    for (int kt = 0; kt < HH; kt += 32) {
        *(bf16x8*)&As[0][ar][akc] = ra0;
        *(bf16x8*)&As[1][ar][akc] = ra1;
        *(bf16x8*)&As[2][ar][akc] = ra2;
        if (bst) {
            *(bf16x8*)&Bs[bp][bnr][bkh]     = rb0;
            *(bf16x8*)&Bs[bp][bnr][bkh + 8] = rb1;
        }
        __syncthreads();
        if (kt + 32 < HH) {
            const short* An = Arow + kt + 32;
            ra0 = *(const bf16x8*)(An);
            ra1 = *(const bf16x8*)(An + psA);
            ra2 = *(const bf16x8*)(An + 2 * psA);
            if (bst) {
                const short* Bn = Brow + kt + 32;
                rb0 = *(const bf16x8*)(Bn);
                rb1 = *(const bf16x8*)(Bn + 8);
            }
        }
        bf16x8 a00 = *(const bf16x8*)&As[0][wr * 32 + fr][fk];
        bf16x8 a01 = *(const bf16x8*)&As[0][wr * 32 + 16 + fr][fk];
        bf16x8 a10 = *(const bf16x8*)&As[1][wr * 32 + fr][fk];
        bf16x8 a11 = *(const bf16x8*)&As[1][wr * 32 + 16 + fr][fk];
        bf16x8 a20 = *(const bf16x8*)&As[2][wr * 32 + fr][fk];
        bf16x8 a21 = *(const bf16x8*)&As[2][wr * 32 + 16 + fr][fk];
        bf16x8 b00 = *(const bf16x8*)&Bs[0][wc * 32 + fr][fk];
        bf16x8 b01 = *(const bf16x8*)&Bs[0][wc * 32 + 16 + fr][fk];
        bf16x8 b10 = *(const bf16x8*)&Bs[1][wc * 32 + fr][fk];
        bf16x8 b11 = *(const bf16x8*)&Bs[1][wc * 32 + 16 + fr][fk];
        bf16x8 b20 = *(const bf16x8*)&Bs[2][wc * 32 + fr][fk];
        bf16x8 b21 = *(const bf16x8*)&Bs[2][wc * 32 + 16 + fr][fk];
        MFMA6(acc00, a00, a10, a20, b00, b10, b20)
        MFMA6(acc01, a00, a10, a20, b01, b11, b21)
        MFMA6(acc10, a01, a11, a21, b00, b10, b20)
        MFMA6(acc11, a01, a11, a21, b01, b11, b21)
        __syncthreads();
    }
    const int orow = (lane >> 4) * 4;
    #pragma unroll
    for (int mf = 0; mf < 2; ++mf) {
        #pragma unroll
        for (int nf = 0; nf < 2; ++nf) {
            f32x4 v = mf == 0 ? (nf == 0 ? acc00 : acc01) : (nf == 0 ? acc10 : acc11);
            int c = n0 + wc * 32 + nf * 16 + fr;
            #pragma unroll
            for (int reg = 0; reg < 4; ++reg) {
                int r = m0 + wr * 32 + mf * 16 + orow + reg;
                if (r >= nrows) continue;
                long rb = (long)(r & 31), rc = (long)(r >> 5);
                float val = v[reg];
                if (O) {
                    float* p = O + rb * sob + rc * soc + c;
                    if (add) val += *p;
                    *p = val;
                }
                if (P) { float* q = P + rb * spb + rc * spc + c; *q += val; }
                if (S) {
                    short h, m, l;
                    split3(val, h, m, l);
                    short* s = S + rb * ssb + rc * ssc + c;
                    s[0] = h; s[psS] = m; s[2 * psS] = l;
                }
            }
        }
    }
}

// ---------------------------------------------------------------------------
__global__ __launch_bounds__(256) void ln_k(float* __restrict__ y,
                                            const float* __restrict__ w,
                                            const float* __restrict__ bia) {
    __shared__ float red[8];
    int row = blockIdx.x;
    float* p = y + (size_t)row * HH;
    int i4 = threadIdx.x * 4;
    float4 v = *(const float4*)&p[i4];
    float s = v.x + v.y + v.z + v.w;
    #pragma unroll
    for (int o = 32; o > 0; o >>= 1) s += __shfl_down(s, o, 64);
    int wid = threadIdx.x >> 6;
    if ((threadIdx.x & 63) == 0) red[wid] = s;
    __syncthreads();
    if (threadIdx.x == 0) red[4] = (red[0] + red[1] + red[2] + red[3]) * (1.f / HH);
    __syncthreads();
    float mu = red[4];
    float dx = v.x - mu, dy = v.y - mu, dz = v.z - mu, dw = v.w - mu;
    float q = dx * dx + dy * dy + dz * dz + dw * dw;
    #pragma unroll
    for (int o = 32; o > 0; o >>= 1) q += __shfl_down(q, o, 64);
    if ((threadIdx.x & 63) == 0) red[wid] = q;
    __syncthreads();
    if (threadIdx.x == 0) red[5] = (red[0] + red[1] + red[2] + red[3]) * (1.f / HH);
    __syncthreads();
    float rs = rsqrtf(red[5] + LN_EPS);
    float4 o4;
    o4.x = dx * rs * w[i4 + 0] + bia[i4 + 0];
    o4.y = dy * rs * w[i4 + 1] + bia[i4 + 1];
    o4.z = dz * rs * w[i4 + 2] + bia[i4 + 2];
    o4.w = dw * rs * w[i4 + 3] + bia[i4 + 3];
    *(float4*)&p[i4] = o4;
}

// ---------------------------------------------------------------------------
extern "C" void kernel_launch(void* const* d_in, const int* in_sizes, int n_in,
                              void* d_out, int out_size, void* d_ws, size_t ws_size,
                              hipStream_t stream) {
    const float* x    = (const float*)d_in[0];
    const float* Wxh  = (const float*)d_in[1];
    const float* Whh  = (const float*)d_in[2];
    const float* ln_w = (const float*)d_in[3];
    const float* ln_b = (const float*)d_in[4];

    const size_t MiB = 1024 * 1024;
    const long HM  = (long)HH * HH;
    const long PS2 = 2048L * HH;
    float* rec  = (float*)d_out;
    float* outp = rec + (size_t)BB * LL * HH;

    const long LH  = (long)LL * HH;
    const long CH8 = (long)C8 * HH;
    const long PB  = (long)PRED * HH;
    const long RS  = (long)HH;
    const long RC  = 32L * HH;
    float* nulf = (float*)nullptr;
    short* nuls = (short*)nullptr;
    char* wsb = (char*)d_ws;

    if (ws_size >= 124 * MiB) {
        // ======== tier A: dual-chain powers + BN=128 step kernels ========
        auto NA = [&](int idx) -> short* { return (short*)wsb + (size_t)idx * 3 * HM; };
        short* MAs[3] = {(short*)(wsb + 78 * MiB), (short*)(wsb + 84 * MiB),
                         (short*)(wsb + 90 * MiB)};
        short* SA0 = (short*)(wsb + 96 * MiB);    // 12 MiB (2048-row splits)
        short* SA1 = (short*)(wsb + 108 * MiB);   // 12 MiB
        short* SBW = SA0;                         // alias, consumed before SA0 live
        float* TPf = (float*)SA1;                 // alias, consumed before SA1 live

        GDv8 D{};
        auto launch = [&](int ng, int ytot) {
            step_g2<<<dim3(8, ytot), 256, 0, stream>>>(D, ng);
        };
        auto g_sq = [&](const short* A_, const short* B_, short* S_, int ybeg) -> GDv {
            GDv v{};
            v.A = A_; v.B = B_; v.O = nullptr; v.P = nullptr; v.S = S_;
            v.sab = HH; v.sac = 32 * HH; v.psA = (int)HM;
            v.ssb = HH; v.ssc = 32 * HH; v.psS = (int)HM;
            v.add = 0; v.nrows = 1024; v.ybeg = ybeg;
            return v;
        };

        // ---- seeds: NA1 = splits(Whh) (= B-splits of M), MA1 = splits(Whh^T)
        transpose_k<<<dim3(32, 32), dim3(32, 8), 0, stream>>>(Whh, TPf);
        split_a<<<dim3(1, HH), 256, 0, stream>>>(Whh, RS, RC, NA(0), RS, RC, HM);
        split_a<<<dim3(1, HH), 256, 0, stream>>>(TPf, RS, RC, MAs[0], RS, RC, HM);
        split_a<<<dim3(1, HH), 256, 0, stream>>>(Wxh, RS, RC, SBW, RS, RC, HM);
        gemm_mx2<<<dim3(8, 128), 256, 0, stream>>>(x, SBW, rec);

        // ---- stage1 (7 sequential steps of 2048 rows) + carried power groups
        split_a<<<dim3(1, 2048), 256, 0, stream>>>(rec, LH, CH8, SA0, RS, RC, PS2);
        short* SAc = SA0;
        short* SAn = SA1;
        for (int o = 1; o < C8; ++o) {
            GDv mn{};
            mn.A = SAc; mn.B = NA(0);
            mn.O = rec + (size_t)o * HH; mn.sob = (int)LH; mn.soc = (int)CH8; mn.add = 1;
            mn.P = nullptr; mn.S = SAn;
            mn.sab = HH; mn.sac = 32 * HH; mn.psA = (int)PS2;
            mn.ssb = HH; mn.ssc = 32 * HH; mn.psS = (int)PS2;
            mn.nrows = 2048; mn.ybeg = 0;
            D.g[0] = mn;
            int ng = 1, yt = 16;
            auto add_sq = [&](const short* A_, const short* B_, short* S_) {
                D.g[ng++] = g_sq(A_, B_, S_, yt); yt += 8;
            };
            switch (o) {
                case 1:  // M2 = M·M ; N2 = N·N
                    add_sq(MAs[0], NA(0), MAs[1]);
                    add_sq(NA(0), MAs[0], NA(1));
                    break;
                case 2:  // M4 ; N3 ; N4
                    add_sq(MAs[1], NA(1), MAs[2]);
                    add_sq(NA(1), MAs[0], NA(2));
                    add_sq(NA(1), MAs[1], NA(3));
                    break;
                case 3:  // N5 ; N6 ; N8
                    add_sq(NA(3), MAs[0], NA(4));
                    add_sq(NA(3), MAs[1], NA(5));
                    add_sq(NA(3), MAs[2], NA(7));
                    break;
                case 4:  // N7 ; M8 (MA1 dead -> slot0)
                    add_sq(NA(2), MAs[2], NA(6));
                    add_sq(MAs[2], NA(3), MAs[0]);
                    break;
                case 5:  // N16 ; M16 (MA2 dead -> slot1)
                    add_sq(NA(7), MAs[0], NA(8));
                    add_sq(MAs[0], NA(7), MAs[1]);
                    break;
                case 6:  // N32 ; M32 (MA4 dead -> slot2)
                    add_sq(NA(8), MAs[1], NA(9));
                    add_sq(MAs[1], NA(8), MAs[2]);
                    break;
                case 7:  // N64 ; M64 (M8 dead -> slot0)
                    add_sq(NA(9), MAs[2], NA(10));
                    add_sq(MAs[2], NA(9), MAs[0]);
                    break;
            }
            launch(ng, yt);
            short* t = SAc; SAc = SAn; SAn = t;
        }
        // chunk-end splits now in SAc (= SA1)

        // ---- Hillis-Steele scan over 64 chunk-ends; N128/M128/N256 ride s=0,1
        short* SRC = SAc;
        short* DST = SAn;
        for (int s = 0; s < 6; ++s) {
            int T = 1 << s;
            int rows_ = (NC8 - T) * 32;
            int yb = (rows_ + 127) / 128;
            GDv mn{};
            mn.A = SRC; mn.B = NA(s == 0 ? 7 : 7 + s);
            mn.O = rec + (size_t)(T * C8 + C8 - 1) * HH;
            mn.sob = (int)LH; mn.soc = (int)CH8; mn.add = 1;
            mn.P = nullptr; mn.S = DST + (size_t)T * RC;
            mn.sab = HH; mn.sac = 32 * HH; mn.psA = (int)PS2;
            mn.ssb = HH; mn.ssc = 32 * HH; mn.psS = (int)PS2;
            mn.nrows = rows_; mn.ybeg = 0;
            D.g[0] = mn;
            int ng = 1, yt = yb;
            if (s == 0) {  // N128 ; M128 (M16 dead -> slot1)
                D.g[ng++] = g_sq(NA(10), MAs[0], NA(11), yt); yt += 8;
                D.g[ng++] = g_sq(MAs[0], NA(10), MAs[1], yt); yt += 8;
            } else if (s == 1) {  // N256
                D.g[ng++] = g_sq(NA(11), MAs[1], NA(12), yt); yt += 8;
            }
            launch(ng, yt);
            copy_splits<<<T * 32, 256, 0, stream>>>(SRC, DST, PS2);
            short* t = SRC; SRC = DST; DST = t;
        }
        short* SFIN = SRC;   // true chunk-end splits (chunk 63 = rows 2016..2047)
        short* SFREE = DST;

        // ---- stage3: ONE batched launch, 7 groups x 2016 rows
        for (int g = 0; g < 7; ++g) {
            GDv v{};
            v.A = SFIN; v.B = NA(g);
            v.O = nullptr; v.S = nullptr;
            v.P = rec + (size_t)(C8 + g) * HH;
            v.spb = (int)LH; v.spc = (int)CH8;
            v.sab = HH; v.sac = 32 * HH; v.psA = (int)PS2;
            v.nrows = 2016; v.ybeg = g * 16;
            D.g[g] = v;
        }
        launch(7, 112);

        // ---- pred: P1..8 batched (8 groups), then ·M^8, ·M^16
        for (int g = 0; g < 8; ++g) {
            GDv v{};
            v.A = SFIN + 63 * RC; v.B = NA(g);
            v.O = outp + (size_t)g * HH; v.sob = (int)PB; v.soc = 0; v.add = 0;
            v.P = nullptr;
            v.S = SFREE + (size_t)g * RC; v.ssb = HH; v.ssc = 0; v.psS = (int)PS2;
            v.sab = HH; v.sac = 0; v.psA = (int)PS2;
            v.nrows = 32; v.ybeg = g;
            D.g[g] = v;
        }
        launch(8, 8);
        {
            GDv v{};
            v.A = SFREE; v.B = NA(7);
            v.O = outp + 8 * HH; v.sob = (int)PB; v.soc = HH; v.add = 0;
            v.P = nullptr;
            v.S = SFREE + 8 * RC; v.ssb = HH; v.ssc = 32 * HH; v.psS = (int)PS2;
            v.sab = HH; v.sac = 32 * HH; v.psA = (int)PS2;
            v.nrows = 256; v.ybeg = 0;
            D.g[0] = v;
            launch(1, 2);
            v.B = NA(8);
            v.O = outp + 16 * HH;
            v.S = nullptr;
            v.nrows = 512;
            D.g[0] = v;
            launch(1, 4);
        }

        ln_k<<<BB * PRED, 256, 0, stream>>>(outp, ln_w, ln_b);
        return;
    }

    // ================= fallback: proven R8 64-MiB tier =================
    {
        float* TP   = (float*)(wsb);
        short* SAP  = (short*)(wsb + 4 * MiB);
        short* SA0  = (short*)(wsb + 10 * MiB);
        short* SA1  = (short*)(wsb + 22 * MiB);
        short* SBM  = (short*)(wsb + 34 * MiB);
        short* SB8  = (short*)(wsb + 40 * MiB);
        short* SB16 = (short*)(wsb + 46 * MiB);
        short* SBr0 = (short*)(wsb + 52 * MiB);
        short* SBr1 = (short*)(wsb + 58 * MiB);

        transpose_k<<<dim3(32, 32), dim3(32, 8), 0, stream>>>(Whh, TP);
        split_a<<<dim3(1, HH), 256, 0, stream>>>(Wxh, RS, RC, SBr0, RS, RC, HM);
        gemm_mx<<<dim3(16, 128), 256, 0, stream>>>(x, SBr0, rec);
        split_a<<<dim3(1, HH), 256, 0, stream>>>(TP, RS, RC, SAP, RS, RC, HM);
        split_t<<<dim3(32, 32), dim3(32, 8), 0, stream>>>(TP, SBM);

        #define SQ64(SAi, SBi, Sot) \
            step_p64<<<dim3(16, 16), 256, 0, stream>>>(SAi, RS, RC, HM, SBi, \
                TP, RS, RC, 0, nulf, 0, 0, Sot, RS, RC, HM, 1024)
        SQ64(SAP, SBM, SA1);
        split_t<<<dim3(32, 32), dim3(32, 8), 0, stream>>>(TP, SBr0);
        SQ64(SA1, SBr0, SAP);
        split_t<<<dim3(32, 32), dim3(32, 8), 0, stream>>>(TP, SBr1);
        SQ64(SAP, SBr1, SA1);
        split_t<<<dim3(32, 32), dim3(32, 8), 0, stream>>>(TP, SB8);
        SQ64(SA1, SB8, SAP);
        split_t<<<dim3(32, 32), dim3(32, 8), 0, stream>>>(TP, SB16);

        split_a<<<dim3(1, 2048), 256, 0, stream>>>(rec, LH, CH8, SA0, RS, RC, PS2);
        for (int o = 1; o < C8; ++o) {
            short* Ain = (o & 1) ? SA0 : SA1;
            short* Sot = (o & 1) ? SA1 : SA0;
            step_p128<<<dim3(16, 16), 512, 0, stream>>>(Ain, RS, RC, PS2, SBM,
                rec + (size_t)o * HH, LH, CH8, 1, nulf, 0, 0,
                Sot, RS, RC, PS2, 2048);
        }
        #define SCAN(SRC, DST, T, SBpow) do { \
            int rows_ = (NC8 - (T)) * 32; \
            step_p128<<<dim3(16, (rows_ + 127) / 128), 512, 0, stream>>>( \
                SRC, RS, RC, PS2, SBpow, \
                rec + (size_t)((T) * C8 + C8 - 1) * HH, LH, CH8, 1, \
                nulf, 0, 0, DST + (size_t)(T) * RC, RS, RC, PS2, rows_); \
            copy_splits<<<(T) * 32, 256, 0, stream>>>(SRC, DST, PS2); \
        } while (0)
        #define SQI(SBi, SBo, last) do { \
            step_p64<<<dim3(16, 16), 256, 0, stream>>>(SAP, RS, RC, HM, SBi, \
                TP, RS, RC, 0, nulf, 0, 0, nuls, 0, 0, HM, 1024); \
            split_t<<<dim3(32, 32), dim3(32, 8), 0, stream>>>(TP, SBo); \
            if (!(last)) split_a<<<dim3(1, HH), 256, 0, stream>>>(TP, RS, RC, SAP, RS, RC, HM); \
        } while (0)
        SCAN(SA1, SA0, 1, SB8);
        SQI(SB16, SBr0, 0);
        SCAN(SA0, SA1, 2, SB16);
        SQI(SBr0, SBr1, 0);
        SCAN(SA1, SA0, 4, SBr0);
        SQI(SBr1, SBr0, 0);
        SCAN(SA0, SA1, 8, SBr1);
        SQI(SBr0, SBr1, 1);
        SCAN(SA1, SA0, 16, SBr0);
        SCAN(SA0, SA1, 32, SBr1);
        for (int o = 0; o < C8 - 1; ++o) {
            short* Ain = (o & 1) ? SA0 : SA1;
            short* Sot = (o & 1) ? SA1 : SA0;
            step_p128<<<dim3(16, 16), 512, 0, stream>>>(Ain, RS, RC, PS2, SBM,
                nulf, 0, 0, 0,
                rec + (size_t)(C8 + o) * HH, LH, CH8,
                (o == C8 - 2) ? nuls : Sot, RS, RC, PS2, 2016);
        }
        step_p<<<dim3(16, 1), 128, 0, stream>>>(SA1 + 63 * RC, RS, 0, PS2, SBM,
            outp, PB, 0, 0, nulf, 0, 0, SA0, RS, 0, PS2);
        step_p<<<dim3(16, 1), 128, 0, stream>>>(SA0, RS, 0, PS2, SBM,
            outp + HH, PB, 0, 0, nulf, 0, 0, SA0 + RC, RS, 0, PS2);
        tr_splits<<<dim3(32, 32, 3), dim3(32, 8), 0, stream>>>(SBM, SAP);
        SQ64(SAP, SBM, nuls);
        split_t<<<dim3(32, 32), dim3(32, 8), 0, stream>>>(TP, SBr0);
        step_p<<<dim3(16, 2), 128, 0, stream>>>(SA0, RS, RC, PS2, SBr0,
            outp + 2 * HH, PB, RS, 0, nulf, 0, 0,
            SA0 + 2 * RC, RS, RC, PS2);
        split_a<<<dim3(1, HH), 256, 0, stream>>>(TP, RS, RC, SAP, RS, RC, HM);
        SQ64(SAP, SBr0, nuls);
        split_t<<<dim3(32, 32), dim3(32, 8), 0, stream>>>(TP, SBr1);
        step_p<<<dim3(16, 4), 128, 0, stream>>>(SA0, RS, RC, PS2, SBr1,
            outp + 4 * HH, PB, RS, 0, nulf, 0, 0,
            SA0 + 4 * RC, RS, RC, PS2);
        step_p<<<dim3(16, 8), 128, 0, stream>>>(SA0, RS, RC, PS2, SB8,
            outp + 8 * HH, PB, RS, 0, nulf, 0, 0,
            SA0 + 8 * RC, RS, RC, PS2);
        step_p64<<<dim3(16, 8), 256, 0, stream>>>(SA0, RS, RC, PS2, SB16,
            outp + 16 * HH, PB, RS, 0, nulf, 0, 0,
            nuls, 0, 0, PS2, 512);
        #undef SQ64
        #undef SCAN
        #undef SQI

        ln_k<<<BB * PRED, 256, 0, stream>>>(outp, ln_w, ln_b);
    }
}

// Round 12
// 1264.364 us; speedup vs baseline: 1.2435x; 1.2435x over previous
//
#include <hip/hip_runtime.h>

#define BB 32
#define LL 512
#define HH 1024
#define PRED 32
#define C8 8             // chunk length
#define NC8 (LL / C8)    // 64 chunks
#define LN_EPS 1e-5f

typedef short bf16x8 __attribute__((ext_vector_type(8)));
typedef short s16x4  __attribute__((ext_vector_type(4)));
typedef float f32x4  __attribute__((ext_vector_type(4)));

static __device__ __forceinline__ void split3(float x, short& h, short& m, short& l) {
    unsigned u = __float_as_uint(x);
    unsigned rh = (u + 0x7fffu + ((u >> 16) & 1u)) & 0xffff0000u;
    h = (short)(rh >> 16);
    float x1 = x - __uint_as_float(rh);
    unsigned u1 = __float_as_uint(x1);
    unsigned rm = (u1 + 0x7fffu + ((u1 >> 16) & 1u)) & 0xffff0000u;
    m = (short)(rm >> 16);
    float x2 = x1 - __uint_as_float(rm);
    unsigned u2 = __float_as_uint(x2);
    unsigned rl = (u2 + 0x7fffu + ((u2 >> 16) & 1u)) & 0xffff0000u;
    l = (short)(rl >> 16);
}

static __device__ __forceinline__ void split2(float x, short& h, short& m) {
    unsigned u = __float_as_uint(x);
    unsigned rh = (u + 0x7fffu + ((u >> 16) & 1u)) & 0xffff0000u;
    h = (short)(rh >> 16);
    float x1 = x - __uint_as_float(rh);
    unsigned u1 = __float_as_uint(x1);
    unsigned rm = (u1 + 0x7fffu + ((u1 >> 16) & 1u)) & 0xffff0000u;
    m = (short)(rm >> 16);
}

#define MFMA6(ACC, AH, AM, AL, BH, BM, BL) \
    ACC = __builtin_amdgcn_mfma_f32_16x16x32_bf16(AL, BH, ACC, 0, 0, 0); \
    ACC = __builtin_amdgcn_mfma_f32_16x16x32_bf16(AH, BL, ACC, 0, 0, 0); \
    ACC = __builtin_amdgcn_mfma_f32_16x16x32_bf16(AM, BM, ACC, 0, 0, 0); \
    ACC = __builtin_amdgcn_mfma_f32_16x16x32_bf16(AM, BH, ACC, 0, 0, 0); \
    ACC = __builtin_amdgcn_mfma_f32_16x16x32_bf16(AH, BM, ACC, 0, 0, 0); \
    ACC = __builtin_amdgcn_mfma_f32_16x16x32_bf16(AH, BH, ACC, 0, 0, 0);

// ---------------------------------------------------------------------------
__global__ __launch_bounds__(256) void transpose_k(const float* __restrict__ in,
                                                   float* __restrict__ out) {
    __shared__ float tile[32][33];
    int bx = blockIdx.x * 32, by = blockIdx.y * 32;
    int tx = threadIdx.x, ty = threadIdx.y;
    #pragma unroll
    for (int i = 0; i < 32; i += 8)
        tile[ty + i][tx] = in[(size_t)(by + ty + i) * HH + bx + tx];
    __syncthreads();
    #pragma unroll
    for (int i = 0; i < 32; i += 8)
        out[(size_t)(bx + ty + i) * HH + by + tx] = tile[tx][ty + i];
}

// ---------------------------------------------------------------------------
__global__ __launch_bounds__(256) void split_a(const float* __restrict__ src, long sb, long sc,
                                               short* __restrict__ dst, long dsb, long dsc,
                                               long ps) {
    int r = blockIdx.y;
    const float* s = src + (long)(r & 31) * sb + (long)(r >> 5) * sc + threadIdx.x * 4;
    short* d = dst + (long)(r & 31) * dsb + (long)(r >> 5) * dsc + threadIdx.x * 4;
    float4 v = *(const float4*)s;
    float xs[4] = {v.x, v.y, v.z, v.w};
    s16x4 vh, vm, vl;
    #pragma unroll
    for (int j = 0; j < 4; ++j) {
        short h, m, l;
        split3(xs[j], h, m, l);
        vh[j] = h; vm[j] = m; vl[j] = l;
    }
    *(s16x4*)(d) = vh;
    *(s16x4*)(d + ps) = vm;
    *(s16x4*)(d + 2 * ps) = vl;
}

// ---------------------------------------------------------------------------
__global__ __launch_bounds__(256) void split_t(const float* __restrict__ in,
                                               short* __restrict__ out) {
    const size_t HM = (size_t)HH * HH;
    __shared__ float tile[32][33];
    int n0 = blockIdx.x * 32, k0 = blockIdx.y * 32;
    int tx = threadIdx.x, ty = threadIdx.y;
    #pragma unroll
    for (int i = 0; i < 32; i += 8)
        tile[ty + i][tx] = in[(size_t)(k0 + ty + i) * HH + n0 + tx];
    __syncthreads();
    #pragma unroll
    for (int i = 0; i < 32; i += 8) {
        float v = tile[tx][ty + i];
        short h, m, l;
        split3(v, h, m, l);
        size_t o = (size_t)(n0 + ty + i) * HH + k0 + tx;
        out[o] = h; out[HM + o] = m; out[2 * HM + o] = l;
    }
}

// ---------------------------------------------------------------------------
__global__ __launch_bounds__(256) void tr_splits(const short* __restrict__ in,
                                                 short* __restrict__ out) {
    const size_t HM = (size_t)HH * HH;
    __shared__ short tile[32][33];
    int p = blockIdx.z;
    int k0 = blockIdx.x * 32, n0 = blockIdx.y * 32;
    int tx = threadIdx.x, ty = threadIdx.y;
    #pragma unroll
    for (int i = 0; i < 32; i += 8)
        tile[ty + i][tx] = in[p * HM + (size_t)(n0 + ty + i) * HH + k0 + tx];
    __syncthreads();
    #pragma unroll
    for (int i = 0; i < 32; i += 8)
        out[p * HM + (size_t)(k0 + ty + i) * HH + n0 + tx] = tile[tx][ty + i];
}

// ---------------------------------------------------------------------------
__global__ __launch_bounds__(256) void copy_splits(const short* __restrict__ src,
                                                   short* __restrict__ dst, long ps) {
    size_t off = (size_t)blockIdx.x * HH + threadIdx.x * 4;
    *(s16x4*)(dst + off)          = *(const s16x4*)(src + off);
    *(s16x4*)(dst + ps + off)     = *(const s16x4*)(src + ps + off);
    *(s16x4*)(dst + 2 * ps + off) = *(const s16x4*)(src + 2 * ps + off);
}

// ---------------------------------------------------------------------------
// gemm_mx: 128x64 tile, bf16 2x2 split (proven R7).
// ---------------------------------------------------------------------------
__global__ __launch_bounds__(256) void gemm_mx(const float* __restrict__ A,
                                               const short* __restrict__ SB,
                                               float* __restrict__ C) {
    const size_t HM = (size_t)HH * HH;
    __shared__ __align__(16) short As2[2][128][40];
    __shared__ __align__(16) short Bs2[2][64][40];
    const int tid = threadIdx.x;
    const int lane = tid & 63;
    const int w = tid >> 6;
    const int n0 = blockIdx.x * 64;
    const int m0 = blockIdx.y * 128;
    const int ar = tid >> 1;
    const int akc = (tid & 1) * 16;
    const float* Arow = A + (size_t)(m0 + ar) * HH + akc;
    const int bp = tid >> 7;
    const int bnr = tid & 63;
    const int bkh = ((tid >> 6) & 1) * 16;
    const short* Brow = SB + bp * HM + (size_t)(n0 + bnr) * HH + bkh;
    const int fr = lane & 15;
    const int fk = (lane >> 4) * 8;

    f32x4 acc[2][4] = {};

    float4 av0 = *(const float4*)(Arow);
    float4 av1 = *(const float4*)(Arow + 4);
    float4 av2 = *(const float4*)(Arow + 8);
    float4 av3 = *(const float4*)(Arow + 12);
    bf16x8 rb0 = *(const bf16x8*)(Brow);
    bf16x8 rb1 = *(const bf16x8*)(Brow + 8);

    for (int kt = 0; kt < HH; kt += 32) {
        float xs[16] = {av0.x, av0.y, av0.z, av0.w, av1.x, av1.y, av1.z, av1.w,
                        av2.x, av2.y, av2.z, av2.w, av3.x, av3.y, av3.z, av3.w};
        bf16x8 vh0, vm0, vh1, vm1;
        #pragma unroll
        for (int j = 0; j < 8; ++j) {
            short h, m;
            split2(xs[j], h, m);
            vh0[j] = h; vm0[j] = m;
            split2(xs[j + 8], h, m);
            vh1[j] = h; vm1[j] = m;
        }
        *(bf16x8*)&As2[0][ar][akc]     = vh0;
        *(bf16x8*)&As2[0][ar][akc + 8] = vh1;
        *(bf16x8*)&As2[1][ar][akc]     = vm0;
        *(bf16x8*)&As2[1][ar][akc + 8] = vm1;
        *(bf16x8*)&Bs2[bp][bnr][bkh]     = rb0;
        *(bf16x8*)&Bs2[bp][bnr][bkh + 8] = rb1;
        __syncthreads();
        if (kt + 32 < HH) {
            const float* An = Arow + kt + 32;
            av0 = *(const float4*)(An);
            av1 = *(const float4*)(An + 4);
            av2 = *(const float4*)(An + 8);
            av3 = *(const float4*)(An + 12);
            const short* Bn = Brow + kt + 32;
            rb0 = *(const bf16x8*)(Bn);
            rb1 = *(const bf16x8*)(Bn + 8);
        }
        bf16x8 ah[2], am[2];
        #pragma unroll
        for (int i = 0; i < 2; ++i) {
            ah[i] = *(const bf16x8*)&As2[0][w * 32 + i * 16 + fr][fk];
            am[i] = *(const bf16x8*)&As2[1][w * 32 + i * 16 + fr][fk];
        }
        #pragma unroll
        for (int j = 0; j < 4; ++j) {
            bf16x8 bh = *(const bf16x8*)&Bs2[0][j * 16 + fr][fk];
            bf16x8 bm = *(const bf16x8*)&Bs2[1][j * 16 + fr][fk];
            #pragma unroll
            for (int i = 0; i < 2; ++i) {
                f32x4 a = acc[i][j];
                a = __builtin_amdgcn_mfma_f32_16x16x32_bf16(am[i], bm, a, 0, 0, 0);
                a = __builtin_amdgcn_mfma_f32_16x16x32_bf16(am[i], bh, a, 0, 0, 0);
                a = __builtin_amdgcn_mfma_f32_16x16x32_bf16(ah[i], bm, a, 0, 0, 0);
                a = __builtin_amdgcn_mfma_f32_16x16x32_bf16(ah[i], bh, a, 0, 0, 0);
                acc[i][j] = a;
            }
        }
        __syncthreads();
    }
    const int orow = (lane >> 4) * 4;
    #pragma unroll
    for (int i = 0; i < 2; ++i)
        #pragma unroll
        for (int j = 0; j < 4; ++j) {
            int c = n0 + j * 16 + fr;
            #pragma unroll
            for (int reg = 0; reg < 4; ++reg) {
                int r = m0 + w * 32 + i * 16 + orow + reg;
                C[(size_t)r * HH + c] = acc[i][j][reg];
            }
        }
}

// ---------------------------------------------------------------------------
// Descriptors for batched multi-group GEMMs.
// ---------------------------------------------------------------------------
struct GDv {
    const short* A; const short* B; float* O; float* P; short* S;
    int sab, sac, psA, sob, soc, spb, spc, ssb, ssc, psS, add, nrows, ybeg;
};
struct GDv16 { GDv g[16]; };

// ---------------------------------------------------------------------------
// step_g: batched bf16x6 MFMA GEMM, 128(M)x64(N), 4 waves (wave tile 32x64).
// Proven R10 body; descriptor array widened to 16.
// ---------------------------------------------------------------------------
__global__ __launch_bounds__(256) void step_g(GDv16 dsc, int ng) {
    const size_t HM = (size_t)HH * HH;
    __shared__ __align__(16) short As[3][128][40];
    __shared__ __align__(16) short Bs[3][64][40];
    const int tid = threadIdx.x;
    const int lane = tid & 63;
    const int w = tid >> 6;
    const int yy = blockIdx.y;
    int gi = 0;
    for (int i = 1; i < ng; ++i)
        if (yy >= dsc.g[i].ybeg) gi = i;
    const GDv d = dsc.g[gi];
    const int n0 = blockIdx.x * 64;
    const int m0 = (yy - d.ybeg) * 128;
    const int ar = tid >> 1;
    const int akh = (tid & 1) * 16;
    const int agr = m0 + ar;
    const short* Arow = d.A + (long)(agr & 31) * d.sab + (long)(agr >> 5) * d.sac + akh;
    const int br = tid >> 2;
    const int bkc = (tid & 3) * 8;
    const short* Brow = d.B + (size_t)(n0 + br) * HH + bkc;
    const int fr = lane & 15;
    const int fk = (lane >> 4) * 8;
    const long psA = d.psA;

    f32x4 acc[2][4] = {};

    bf16x8 ra[6], rb[3];
    #pragma unroll
    for (int p = 0; p < 3; ++p) {
        ra[2 * p]     = *(const bf16x8*)(Arow + p * psA);
        ra[2 * p + 1] = *(const bf16x8*)(Arow + p * psA + 8);
        rb[p]         = *(const bf16x8*)(Brow + p * HM);
    }
    for (int kt = 0; kt < HH; kt += 32) {
        #pragma unroll
        for (int p = 0; p < 3; ++p) {
            *(bf16x8*)&As[p][ar][akh]     = ra[2 * p];
            *(bf16x8*)&As[p][ar][akh + 8] = ra[2 * p + 1];
            *(bf16x8*)&Bs[p][br][bkc]     = rb[p];
        }
        __syncthreads();
        if (kt + 32 < HH) {
            #pragma unroll
            for (int p = 0; p < 3; ++p) {
                ra[2 * p]     = *(const bf16x8*)(Arow + p * psA + kt + 32);
                ra[2 * p + 1] = *(const bf16x8*)(Arow + p * psA + kt + 40);
                rb[p]         = *(const bf16x8*)(Brow + p * HM + kt + 32);
            }
        }
        bf16x8 af[3][2], bfr[3][4];
        #pragma unroll
        for (int p = 0; p < 3; ++p) {
            #pragma unroll
            for (int mf = 0; mf < 2; ++mf)
                af[p][mf] = *(const bf16x8*)&As[p][w * 32 + mf * 16 + fr][fk];
            #pragma unroll
            for (int nf = 0; nf < 4; ++nf)
                bfr[p][nf] = *(const bf16x8*)&Bs[p][nf * 16 + fr][fk];
        }
        #pragma unroll
        for (int mf = 0; mf < 2; ++mf)
            #pragma unroll
            for (int nf = 0; nf < 4; ++nf) {
                MFMA6(acc[mf][nf], af[0][mf], af[1][mf], af[2][mf],
                      bfr[0][nf], bfr[1][nf], bfr[2][nf])
            }
        __syncthreads();
    }
    const int orow = (lane >> 4) * 4;
    #pragma unroll
    for (int mf = 0; mf < 2; ++mf)
        #pragma unroll
        for (int nf = 0; nf < 4; ++nf) {
            int c = n0 + nf * 16 + fr;
            #pragma unroll
            for (int reg = 0; reg < 4; ++reg) {
                int r = m0 + w * 32 + mf * 16 + orow + reg;
                if (r >= d.nrows) continue;
                long rb_ = (long)(r & 31), rc_ = (long)(r >> 5);
                float val = acc[mf][nf][reg];
                if (d.O) {
                    float* p = d.O + rb_ * d.sob + rc_ * d.soc + c;
                    if (d.add) val += *p;
                    *p = val;
                }
                if (d.P) {
                    float* q = d.P + rb_ * d.spb + rc_ * d.spc + c;
                    *q += val;
                }
                if (d.S) {
                    short h, m, l;
                    split3(val, h, m, l);
                    short* s = d.S + rb_ * d.ssb + rc_ * d.ssc + c;
                    s[0] = h; s[d.psS] = m; s[2 * (long)d.psS] = l;
                }
            }
        }
}

// ---------------------------------------------------------------------------
// step_g64: batched bf16x6 MFMA GEMM, 64(M)x64(N), 4 waves (2x2, wave tile
// 32x32). Body = proven step_p64; group select = proven step_g. For
// underfilled launches (scan tails).
// ---------------------------------------------------------------------------
__global__ __launch_bounds__(256) void step_g64(GDv16 dsc, int ng) {
    const size_t HM = (size_t)HH * HH;
    __shared__ __align__(16) short As[3][64][40];
    __shared__ __align__(16) short Bs[3][64][40];
    const int tid = threadIdx.x;
    const int lane = tid & 63;
    const int w = tid >> 6;
    const int wr = w & 1;
    const int wc = w >> 1;
    const int yy = blockIdx.y;
    int gi = 0;
    for (int i = 1; i < ng; ++i)
        if (yy >= dsc.g[i].ybeg) gi = i;
    const GDv d = dsc.g[gi];
    const int n0 = blockIdx.x * 64;
    const int m0 = (yy - d.ybeg) * 64;
    const int ar = tid >> 2;
    const int akc = (tid & 3) * 8;
    const int agr = m0 + ar;
    const short* Arow = d.A + (long)(agr & 31) * d.sab + (long)(agr >> 5) * d.sac + akc;
    const short* Brow = d.B + (size_t)(n0 + ar) * HH + akc;
    const int fr = lane & 15;
    const int fk = (lane >> 4) * 8;
    const long psA = d.psA;

    f32x4 acc00 = 0, acc01 = 0, acc10 = 0, acc11 = 0;

    bf16x8 ra0 = *(const bf16x8*)(Arow);
    bf16x8 ra1 = *(const bf16x8*)(Arow + psA);
    bf16x8 ra2 = *(const bf16x8*)(Arow + 2 * psA);
    bf16x8 rb0 = *(const bf16x8*)(Brow);
    bf16x8 rb1 = *(const bf16x8*)(Brow + HM);
    bf16x8 rb2 = *(const bf16x8*)(Brow + 2 * HM);

    for (int kt = 0; kt < HH; kt += 32) {
        *(bf16x8*)&As[0][ar][akc] = ra0;
        *(bf16x8*)&As[1][ar][akc] = ra1;
        *(bf16x8*)&As[2][ar][akc] = ra2;
        *(bf16x8*)&Bs[0][ar][akc] = rb0;
        *(bf16x8*)&Bs[1][ar][akc] = rb1;
        *(bf16x8*)&Bs[2][ar][akc] = rb2;
        __syncthreads();
        if (kt + 32 < HH) {
            const short* An = Arow + kt + 32;
            const short* Bn = Brow + kt + 32;
            ra0 = *(const bf16x8*)(An);
            ra1 = *(const bf16x8*)(An + psA);
            ra2 = *(const bf16x8*)(An + 2 * psA);
            rb0 = *(const bf16x8*)(Bn);
            rb1 = *(const bf16x8*)(Bn + HM);
            rb2 = *(const bf16x8*)(Bn + 2 * HM);
        }
        bf16x8 a00 = *(const bf16x8*)&As[0][wr * 32 + fr][fk];
        bf16x8 a01 = *(const bf16x8*)&As[0][wr * 32 + 16 + fr][fk];
        bf16x8 a10 = *(const bf16x8*)&As[1][wr * 32 + fr][fk];
        bf16x8 a11 = *(const bf16x8*)&As[1][wr * 32 + 16 + fr][fk];
        bf16x8 a20 = *(const bf16x8*)&As[2][wr * 32 + fr][fk];
        bf16x8 a21 = *(const bf16x8*)&As[2][wr * 32 + 16 + fr][fk];
        bf16x8 b00 = *(const bf16x8*)&Bs[0][wc * 32 + fr][fk];
        bf16x8 b01 = *(const bf16x8*)&Bs[0][wc * 32 + 16 + fr][fk];
        bf16x8 b10 = *(const bf16x8*)&Bs[1][wc * 32 + fr][fk];
        bf16x8 b11 = *(const bf16x8*)&Bs[1][wc * 32 + 16 + fr][fk];
        bf16x8 b20 = *(const bf16x8*)&Bs[2][wc * 32 + fr][fk];
        bf16x8 b21 = *(const bf16x8*)&Bs[2][wc * 32 + 16 + fr][fk];
        MFMA6(acc00, a00, a10, a20, b00, b10, b20)
        MFMA6(acc01, a00, a10, a20, b01, b11, b21)
        MFMA6(acc10, a01, a11, a21, b00, b10, b20)
        MFMA6(acc11, a01, a11, a21, b01, b11, b21)
        __syncthreads();
    }
    const int orow = (lane >> 4) * 4;
    #pragma unroll
    for (int mf = 0; mf < 2; ++mf) {
        #pragma unroll
        for (int nf = 0; nf < 2; ++nf) {
            f32x4 v = mf == 0 ? (nf == 0 ? acc00 : acc01) : (nf == 0 ? acc10 : acc11);
            int c = n0 + wc * 32 + nf * 16 + fr;
            #pragma unroll
            for (int reg = 0; reg < 4; ++reg) {
                int r = m0 + wr * 32 + mf * 16 + orow + reg;
                if (r >= d.nrows) continue;
                long rb = (long)(r & 31), rc = (long)(r >> 5);
                float val = v[reg];
                if (d.O) {
                    float* p = d.O + rb * d.sob + rc * d.soc + c;
                    if (d.add) val += *p;
                    *p = val;
                }
                if (d.P) { float* q = d.P + rb * d.spb + rc * d.spc + c; *q += val; }
                if (d.S) {
                    short h, m, l;
                    split3(val, h, m, l);
                    short* s = d.S + rb * d.ssb + rc * d.ssc + c;
                    s[0] = h; s[d.psS] = m; s[2 * (long)d.psS] = l;
                }
            }
        }
    }
}

// ---------------------------------------------------------------------------
// step_p / step_p64 / step_p128: proven kernels kept for the 64-MiB fallback.
// ---------------------------------------------------------------------------
__global__ __launch_bounds__(128) void step_p(
    const short* __restrict__ SA, long sab, long sac, long psA,
    const short* __restrict__ SB,
    float* __restrict__ O, long sob, long soc, int add,
    float* __restrict__ P, long spb, long spc,
    short* __restrict__ S, long ssb, long ssc, long psS) {
    const size_t HM = (size_t)HH * HH;
    __shared__ __align__(16) short As[3][32][40];
    __shared__ __align__(16) short Bs[3][64][40];
    const int tid = threadIdx.x;
    const int lane = tid & 63;
    const int w = tid >> 6;
    const int n0 = blockIdx.x * 64;
    const int m0 = blockIdx.y * 32;
    const int ar = tid >> 2;
    const int akc = (tid & 3) * 8;
    const int agr = m0 + ar;
    const short* Arow = SA + (long)(agr & 31) * sab + (long)(agr >> 5) * sac + akc;
    const int bnr = tid & 63;
    const int bkh = (tid >> 6) * 16;
    const short* Brow = SB + (size_t)(n0 + bnr) * HH + bkh;
    const int fr = lane & 15;
    const int fk = (lane >> 4) * 8;
    f32x4 acc00 = 0, acc01 = 0, acc10 = 0, acc11 = 0;
    bf16x8 ra0 = *(const bf16x8*)(Arow);
    bf16x8 ra1 = *(const bf16x8*)(Arow + psA);
    bf16x8 ra2 = *(const bf16x8*)(Arow + 2 * psA);
    bf16x8 rb0 = *(const bf16x8*)(Brow);
    bf16x8 rb1 = *(const bf16x8*)(Brow + 8);
    bf16x8 rb2 = *(const bf16x8*)(Brow + HM);
    bf16x8 rb3 = *(const bf16x8*)(Brow + HM + 8);
    bf16x8 rb4 = *(const bf16x8*)(Brow + 2 * HM);
    bf16x8 rb5 = *(const bf16x8*)(Brow + 2 * HM + 8);
    for (int kt = 0; kt < HH; kt += 32) {
        *(bf16x8*)&As[0][ar][akc] = ra0;
        *(bf16x8*)&As[1][ar][akc] = ra1;
        *(bf16x8*)&As[2][ar][akc] = ra2;
        *(bf16x8*)&Bs[0][bnr][bkh] = rb0;
        *(bf16x8*)&Bs[0][bnr][bkh + 8] = rb1;
        *(bf16x8*)&Bs[1][bnr][bkh] = rb2;
        *(bf16x8*)&Bs[1][bnr][bkh + 8] = rb3;
        *(bf16x8*)&Bs[2][bnr][bkh] = rb4;
        *(bf16x8*)&Bs[2][bnr][bkh + 8] = rb5;
        __syncthreads();
        if (kt + 32 < HH) {
            const short* An = Arow + kt + 32;
            const short* Bn = Brow + kt + 32;
            ra0 = *(const bf16x8*)(An);
            ra1 = *(const bf16x8*)(An + psA);
            ra2 = *(const bf16x8*)(An + 2 * psA);
            rb0 = *(const bf16x8*)(Bn);
            rb1 = *(const bf16x8*)(Bn + 8);
            rb2 = *(const bf16x8*)(Bn + HM);
            rb3 = *(const bf16x8*)(Bn + HM + 8);
            rb4 = *(const bf16x8*)(Bn + 2 * HM);
            rb5 = *(const bf16x8*)(Bn + 2 * HM + 8);
        }
        bf16x8 a00 = *(const bf16x8*)&As[0][fr][fk];
        bf16x8 a01 = *(const bf16x8*)&As[0][16 + fr][fk];
        bf16x8 a10 = *(const bf16x8*)&As[1][fr][fk];
        bf16x8 a11 = *(const bf16x8*)&As[1][16 + fr][fk];
        bf16x8 a20 = *(const bf16x8*)&As[2][fr][fk];
        bf16x8 a21 = *(const bf16x8*)&As[2][16 + fr][fk];
        bf16x8 b00 = *(const bf16x8*)&Bs[0][w * 32 + fr][fk];
        bf16x8 b01 = *(const bf16x8*)&Bs[0][w * 32 + 16 + fr][fk];
        bf16x8 b10 = *(const bf16x8*)&Bs[1][w * 32 + fr][fk];
        bf16x8 b11 = *(const bf16x8*)&Bs[1][w * 32 + 16 + fr][fk];
        bf16x8 b20 = *(const bf16x8*)&Bs[2][w * 32 + fr][fk];
        bf16x8 b21 = *(const bf16x8*)&Bs[2][w * 32 + 16 + fr][fk];
        MFMA6(acc00, a00, a10, a20, b00, b10, b20)
        MFMA6(acc01, a00, a10, a20, b01, b11, b21)
        MFMA6(acc10, a01, a11, a21, b00, b10, b20)
        MFMA6(acc11, a01, a11, a21, b01, b11, b21)
        __syncthreads();
    }
    const int orow = (lane >> 4) * 4;
    #pragma unroll
    for (int mf = 0; mf < 2; ++mf) {
        #pragma unroll
        for (int nf = 0; nf < 2; ++nf) {
            f32x4 v = mf == 0 ? (nf == 0 ? acc00 : acc01) : (nf == 0 ? acc10 : acc11);
            int c = n0 + w * 32 + nf * 16 + fr;
            #pragma unroll
            for (int reg = 0; reg < 4; ++reg) {
                int r = m0 + mf * 16 + orow + reg;
                long rb = (long)(r & 31), rc = (long)(r >> 5);
                float val = v[reg];
                if (O) {
                    float* p = O + rb * sob + rc * soc + c;
                    if (add) val += *p;
                    *p = val;
                }
                if (P) { float* q = P + rb * spb + rc * spc + c; *q += val; }
                if (S) {
                    short h, m, l;
                    split3(val, h, m, l);
                    short* s = S + rb * ssb + rc * ssc + c;
                    s[0] = h; s[psS] = m; s[2 * psS] = l;
                }
            }
        }
    }
}

__global__ __launch_bounds__(256) void step_p64(
    const short* __restrict__ SA, long sab, long sac, long psA,
    const short* __restrict__ SB,
    float* __restrict__ O, long sob, long soc, int add,
    float* __restrict__ P, long spb, long spc,
    short* __restrict__ S, long ssb, long ssc, long psS,
    int nrows) {
    const size_t HM = (size_t)HH * HH;
    __shared__ __align__(16) short As[3][64][40];
    __shared__ __align__(16) short Bs[3][64][40];
    const int tid = threadIdx.x;
    const int lane = tid & 63;
    const int w = tid >> 6;
    const int wr = w & 1;
    const int wc = w >> 1;
    const int n0 = blockIdx.x * 64;
    const int m0 = blockIdx.y * 64;
    const int ar = tid >> 2;
    const int akc = (tid & 3) * 8;
    const int agr = m0 + ar;
    const short* Arow = SA + (long)(agr & 31) * sab + (long)(agr >> 5) * sac + akc;
    const short* Brow = SB + (size_t)(n0 + ar) * HH + akc;
    const int fr = lane & 15;
    const int fk = (lane >> 4) * 8;
    f32x4 acc00 = 0, acc01 = 0, acc10 = 0, acc11 = 0;
    bf16x8 ra0 = *(const bf16x8*)(Arow);
    bf16x8 ra1 = *(const bf16x8*)(Arow + psA);
    bf16x8 ra2 = *(const bf16x8*)(Arow + 2 * psA);
    bf16x8 rb0 = *(const bf16x8*)(Brow);
    bf16x8 rb1 = *(const bf16x8*)(Brow + HM);
    bf16x8 rb2 = *(const bf16x8*)(Brow + 2 * HM);
    for (int kt = 0; kt < HH; kt += 32) {
        *(bf16x8*)&As[0][ar][akc] = ra0;
        *(bf16x8*)&As[1][ar][akc] = ra1;
        *(bf16x8*)&As[2][ar][akc] = ra2;
        *(bf16x8*)&Bs[0][ar][akc] = rb0;
        *(bf16x8*)&Bs[1][ar][akc] = rb1;
        *(bf16x8*)&Bs[2][ar][akc] = rb2;
        __syncthreads();
        if (kt + 32 < HH) {
            const short* An = Arow + kt + 32;
            const short* Bn = Brow + kt + 32;
            ra0 = *(const bf16x8*)(An);
            ra1 = *(const bf16x8*)(An + psA);
            ra2 = *(const bf16x8*)(An + 2 * psA);
            rb0 = *(const bf16x8*)(Bn);
            rb1 = *(const bf16x8*)(Bn + HM);
            rb2 = *(const bf16x8*)(Bn + 2 * HM);
        }
        bf16x8 a00 = *(const bf16x8*)&As[0][wr * 32 + fr][fk];
        bf16x8 a01 = *(const bf16x8*)&As[0][wr * 32 + 16 + fr][fk];
        bf16x8 a10 = *(const bf16x8*)&As[1][wr * 32 + fr][fk];
        bf16x8 a11 = *(const bf16x8*)&As[1][wr * 32 + 16 + fr][fk];
        bf16x8 a20 = *(const bf16x8*)&As[2][wr * 32 + fr][fk];
        bf16x8 a21 = *(const bf16x8*)&As[2][wr * 32 + 16 + fr][fk];
        bf16x8 b00 = *(const bf16x8*)&Bs[0][wc * 32 + fr][fk];
        bf16x8 b01 = *(const bf16x8*)&Bs[0][wc * 32 + 16 + fr][fk];
        bf16x8 b10 = *(const bf16x8*)&Bs[1][wc * 32 + fr][fk];
        bf16x8 b11 = *(const bf16x8*)&Bs[1][wc * 32 + 16 + fr][fk];
        bf16x8 b20 = *(const bf16x8*)&Bs[2][wc * 32 + fr][fk];
        bf16x8 b21 = *(const bf16x8*)&Bs[2][wc * 32 + 16 + fr][fk];
        MFMA6(acc00, a00, a10, a20, b00, b10, b20)
        MFMA6(acc01, a00, a10, a20, b01, b11, b21)
        MFMA6(acc10, a01, a11, a21, b00, b10, b20)
        MFMA6(acc11, a01, a11, a21, b01, b11, b21)
        __syncthreads();
    }
    const int orow = (lane >> 4) * 4;
    #pragma unroll
    for (int mf = 0; mf < 2; ++mf) {
        #pragma unroll
        for (int nf = 0; nf < 2; ++nf) {
            f32x4 v = mf == 0 ? (nf == 0 ? acc00 : acc01) : (nf == 0 ? acc10 : acc11);
            int c = n0 + wc * 32 + nf * 16 + fr;
            #pragma unroll
            for (int reg = 0; reg < 4; ++reg) {
                int r = m0 + wr * 32 + mf * 16 + orow + reg;
                if (r >= nrows) continue;
                long rb = (long)(r & 31), rc = (long)(r >> 5);
                float val = v[reg];
                if (O) {
                    float* p = O + rb * sob + rc * soc + c;
                    if (add) val += *p;
                    *p = val;
                }
                if (P) { float* q = P + rb * spb + rc * spc + c; *q += val; }
                if (S) {
                    short h, m, l;
                    split3(val, h, m, l);
                    short* s = S + rb * ssb + rc * ssc + c;
                    s[0] = h; s[psS] = m; s[2 * psS] = l;
                }
            }
        }
    }
}

__global__ __launch_bounds__(512) void step_p128(
    const short* __restrict__ SA, long sab, long sac, long psA,
    const short* __restrict__ SB,
    float* __restrict__ O, long sob, long soc, int add,
    float* __restrict__ P, long spb, long spc,
    short* __restrict__ S, long ssb, long ssc, long psS,
    int nrows) {
    const size_t HM = (size_t)HH * HH;
    __shared__ __align__(16) short As[3][128][40];
    __shared__ __align__(16) short Bs[3][64][40];
    const int tid = threadIdx.x;
    const int lane = tid & 63;
    const int w = tid >> 6;
    const int wr = w & 3;
    const int wc = w >> 2;
    const int n0 = blockIdx.x * 64;
    const int m0 = blockIdx.y * 128;
    const int ar = tid >> 2;
    const int akc = (tid & 3) * 8;
    const int agr = m0 + ar;
    const short* Arow = SA + (long)(agr & 31) * sab + (long)(agr >> 5) * sac + akc;
    const bool bst = (tid < 384);
    const int bp = (tid >> 7) == 3 ? 2 : (tid >> 7);
    const int bt = tid & 127;
    const int bnr = bt >> 1;
    const int bkh = (bt & 1) * 16;
    const short* Brow = SB + (size_t)bp * HM + (size_t)(n0 + bnr) * HH + bkh;
    const int fr = lane & 15;
    const int fk = (lane >> 4) * 8;
    f32x4 acc00 = 0, acc01 = 0, acc10 = 0, acc11 = 0;
    bf16x8 ra0 = *(const bf16x8*)(Arow);
    bf16x8 ra1 = *(const bf16x8*)(Arow + psA);
    bf16x8 ra2 = *(const bf16x8*)(Arow + 2 * psA);
    bf16x8 rb0 = {}, rb1 = {};
    if (bst) { rb0 = *(const bf16x8*)(Brow); rb1 = *(const bf16x8*)(Brow + 8); }
    for (int kt = 0; kt < HH; kt += 32) {
        *(bf16x8*)&As[0][ar][akc] = ra0;
        *(bf16x8*)&As[1][ar][akc] = ra1;
        *(bf16x8*)&As[2][ar][akc] = ra2;
        if (bst) {
            *(bf16x8*)&Bs[bp][bnr][bkh]     = rb0;
            *(bf16x8*)&Bs[bp][bnr][bkh + 8] = rb1;
        }
        __syncthreads();
        if (kt + 32 < HH) {
            const short* An = Arow + kt + 32;
            ra0 = *(const bf16x8*)(An);
            ra1 = *(const bf16x8*)(An + psA);
            ra2 = *(const bf16x8*)(An + 2 * psA);
            if (bst) {
                const short* Bn = Brow + kt + 32;
                rb0 = *(const bf16x8*)(Bn);
                rb1 = *(const bf16x8*)(Bn + 8);
            }
        }
        bf16x8 a00 = *(const bf16x8*)&As[0][wr * 32 + fr][fk];
        bf16x8 a01 = *(const bf16x8*)&As[0][wr * 32 + 16 + fr][fk];
        bf16x8 a10 = *(const bf16x8*)&As[1][wr * 32 + fr][fk];
        bf16x8 a11 = *(const bf16x8*)&As[1][wr * 32 + 16 + fr][fk];
        bf16x8 a20 = *(const bf16x8*)&As[2][wr * 32 + fr][fk];
        bf16x8 a21 = *(const bf16x8*)&As[2][wr * 32 + 16 + fr][fk];
        bf16x8 b00 = *(const bf16x8*)&Bs[0][wc * 32 + fr][fk];
        bf16x8 b01 = *(const bf16x8*)&Bs[0][wc * 32 + 16 + fr][fk];
        bf16x8 b10 = *(const bf16x8*)&Bs[1][wc * 32 + fr][fk];
        bf16x8 b11 = *(const bf16x8*)&Bs[1][wc * 32 + 16 + fr][fk];
        bf16x8 b20 = *(const bf16x8*)&Bs[2][wc * 32 + fr][fk];
        bf16x8 b21 = *(const bf16x8*)&Bs[2][wc * 32 + 16 + fr][fk];
        MFMA6(acc00, a00, a10, a20, b00, b10, b20)
        MFMA6(acc01, a00, a10, a20, b01, b11, b21)
        MFMA6(acc10, a01, a11, a21, b00, b10, b20)
        MFMA6(acc11, a01, a11, a21, b01, b11, b21)
        __syncthreads();
    }
    const int orow = (lane >> 4) * 4;
    #pragma unroll
    for (int mf = 0; mf < 2; ++mf) {
        #pragma unroll
        for (int nf = 0; nf < 2; ++nf) {
            f32x4 v = mf == 0 ? (nf == 0 ? acc00 : acc01) : (nf == 0 ? acc10 : acc11);
            int c = n0 + wc * 32 + nf * 16 + fr;
            #pragma unroll
            for (int reg = 0; reg < 4; ++reg) {
                int r = m0 + wr * 32 + mf * 16 + orow + reg;
                if (r >= nrows) continue;
                long rb = (long)(r & 31), rc = (long)(r >> 5);
                float val = v[reg];
                if (O) {
                    float* p = O + rb * sob + rc * soc + c;
                    if (add) val += *p;
                    *p = val;
                }
                if (P) { float* q = P + rb * spb + rc * spc + c; *q += val; }
                if (S) {
                    short h, m, l;
                    split3(val, h, m, l);
                    short* s = S + rb * ssb + rc * ssc + c;
                    s[0] = h; s[psS] = m; s[2 * psS] = l;
                }
            }
        }
    }
}

// ---------------------------------------------------------------------------
__global__ __launch_bounds__(256) void ln_k(float* __restrict__ y,
                                            const float* __restrict__ w,
                                            const float* __restrict__ bia) {
    __shared__ float red[8];
    int row = blockIdx.x;
    float* p = y + (size_t)row * HH;
    int i4 = threadIdx.x * 4;
    float4 v = *(const float4*)&p[i4];
    float s = v.x + v.y + v.z + v.w;
    #pragma unroll
    for (int o = 32; o > 0; o >>= 1) s += __shfl_down(s, o, 64);
    int wid = threadIdx.x >> 6;
    if ((threadIdx.x & 63) == 0) red[wid] = s;
    __syncthreads();
    if (threadIdx.x == 0) red[4] = (red[0] + red[1] + red[2] + red[3]) * (1.f / HH);
    __syncthreads();
    float mu = red[4];
    float dx = v.x - mu, dy = v.y - mu, dz = v.z - mu, dw = v.w - mu;
    float q = dx * dx + dy * dy + dz * dz + dw * dw;
    #pragma unroll
    for (int o = 32; o > 0; o >>= 1) q += __shfl_down(q, o, 64);
    if ((threadIdx.x & 63) == 0) red[wid] = q;
    __syncthreads();
    if (threadIdx.x == 0) red[5] = (red[0] + red[1] + red[2] + red[3]) * (1.f / HH);
    __syncthreads();
    float rs = rsqrtf(red[5] + LN_EPS);
    float4 o4;
    o4.x = dx * rs * w[i4 + 0] + bia[i4 + 0];
    o4.y = dy * rs * w[i4 + 1] + bia[i4 + 1];
    o4.z = dz * rs * w[i4 + 2] + bia[i4 + 2];
    o4.w = dw * rs * w[i4 + 3] + bia[i4 + 3];
    *(float4*)&p[i4] = o4;
}

// ---------------------------------------------------------------------------
extern "C" void kernel_launch(void* const* d_in, const int* in_sizes, int n_in,
                              void* d_out, int out_size, void* d_ws, size_t ws_size,
                              hipStream_t stream) {
    const float* x    = (const float*)d_in[0];
    const float* Wxh  = (const float*)d_in[1];
    const float* Whh  = (const float*)d_in[2];
    const float* ln_w = (const float*)d_in[3];
    const float* ln_b = (const float*)d_in[4];

    const size_t MiB = 1024 * 1024;
    const long HM  = (long)HH * HH;
    const long PS2 = 2048L * HH;
    float* rec  = (float*)d_out;
    float* outp = rec + (size_t)BB * LL * HH;

    const long LH  = (long)LL * HH;
    const long CH8 = (long)C8 * HH;
    const long PB  = (long)PRED * HH;
    const long RS  = (long)HH;
    const long RC  = 32L * HH;
    float* nulf = (float*)nullptr;
    short* nuls = (short*)nullptr;
    char* wsb = (char*)d_ws;

    if (ws_size >= 124 * MiB) {
        // ======== tier A: R10 structure + step_g64 scan tails + merged pred ========
        auto NA = [&](int idx) -> short* { return (short*)wsb + (size_t)idx * 3 * HM; };
        short* MAs[3] = {(short*)(wsb + 78 * MiB), (short*)(wsb + 84 * MiB),
                         (short*)(wsb + 90 * MiB)};
        short* SA0 = (short*)(wsb + 96 * MiB);    // 12 MiB (2048-row splits)
        short* SA1 = (short*)(wsb + 108 * MiB);   // 12 MiB
        short* SBW = SA0;                         // alias, consumed before SA0 live
        float* TPf = (float*)SA1;                 // alias, consumed before SA1 live

        GDv16 D{};
        auto launch = [&](int ng, int ytot) {
            step_g<<<dim3(16, ytot), 256, 0, stream>>>(D, ng);
        };
        auto launch64 = [&](int ng, int ytot) {
            step_g64<<<dim3(16, ytot), 256, 0, stream>>>(D, ng);
        };
        auto g_sq = [&](const short* A_, const short* B_, short* S_, int ybeg) -> GDv {
            GDv v{};
            v.A = A_; v.B = B_; v.O = nullptr; v.P = nullptr; v.S = S_;
            v.sab = HH; v.sac = 32 * HH; v.psA = (int)HM;
            v.ssb = HH; v.ssc = 32 * HH; v.psS = (int)HM;
            v.add = 0; v.nrows = 1024; v.ybeg = ybeg;
            return v;
        };

        // ---- seeds: NA1 = splits(Whh) (= B-splits of M), MA1 = splits(Whh^T)
        transpose_k<<<dim3(32, 32), dim3(32, 8), 0, stream>>>(Whh, TPf);
        split_a<<<dim3(1, HH), 256, 0, stream>>>(Whh, RS, RC, NA(0), RS, RC, HM);
        split_a<<<dim3(1, HH), 256, 0, stream>>>(TPf, RS, RC, MAs[0], RS, RC, HM);
        split_a<<<dim3(1, HH), 256, 0, stream>>>(Wxh, RS, RC, SBW, RS, RC, HM);
        gemm_mx<<<dim3(16, 128), 256, 0, stream>>>(x, SBW, rec);

        // ---- stage1 (7 sequential steps of 2048 rows) + carried power groups
        split_a<<<dim3(1, 2048), 256, 0, stream>>>(rec, LH, CH8, SA0, RS, RC, PS2);
        short* SAc = SA0;
        short* SAn = SA1;
        for (int o = 1; o < C8; ++o) {
            GDv mn{};
            mn.A = SAc; mn.B = NA(0);
            mn.O = rec + (size_t)o * HH; mn.sob = (int)LH; mn.soc = (int)CH8; mn.add = 1;
            mn.P = nullptr; mn.S = SAn;
            mn.sab = HH; mn.sac = 32 * HH; mn.psA = (int)PS2;
            mn.ssb = HH; mn.ssc = 32 * HH; mn.psS = (int)PS2;
            mn.nrows = 2048; mn.ybeg = 0;
            D.g[0] = mn;
            int ng = 1, yt = 16;
            auto add_sq = [&](const short* A_, const short* B_, short* S_) {
                D.g[ng++] = g_sq(A_, B_, S_, yt); yt += 8;
            };
            switch (o) {
                case 1:  // M2 = M·M ; N2 = N·N
                    add_sq(MAs[0], NA(0), MAs[1]);
                    add_sq(NA(0), MAs[0], NA(1));
                    break;
                case 2:  // M4 ; N3 ; N4
                    add_sq(MAs[1], NA(1), MAs[2]);
                    add_sq(NA(1), MAs[0], NA(2));
                    add_sq(NA(1), MAs[1], NA(3));
                    break;
                case 3:  // N5 ; N6 ; N8
                    add_sq(NA(3), MAs[0], NA(4));
                    add_sq(NA(3), MAs[1], NA(5));
                    add_sq(NA(3), MAs[2], NA(7));
                    break;
                case 4:  // N7 ; M8 (MA1 dead -> slot0)
                    add_sq(NA(2), MAs[2], NA(6));
                    add_sq(MAs[2], NA(3), MAs[0]);
                    break;
                case 5:  // N16 ; M16 (MA2 dead -> slot1)
                    add_sq(NA(7), MAs[0], NA(8));
                    add_sq(MAs[0], NA(7), MAs[1]);
                    break;
                case 6:  // N32 ; M32 (MA4 dead -> slot2)
                    add_sq(NA(8), MAs[1], NA(9));
                    add_sq(MAs[1], NA(8), MAs[2]);
                    break;
                case 7:  // N64 ; M64 (M8 dead -> slot0)
                    add_sq(NA(9), MAs[2], NA(10));
                    add_sq(MAs[2], NA(9), MAs[0]);
                    break;
            }
            launch(ng, yt);
            short* t = SAc; SAc = SAn; SAn = t;
        }
        // chunk-end splits now in SAc (= SA1)

        // ---- Hillis-Steele scan over 64 chunk-ends
        // s=0,1 carry power riders (step_g, BM=128); s=2..5 use step_g64 (BM=64).
        short* SRC = SAc;
        short* DST = SAn;
        for (int s = 0; s < 6; ++s) {
            int T = 1 << s;
            int rows_ = (NC8 - T) * 32;
            GDv mn{};
            mn.A = SRC; mn.B = NA(s == 0 ? 7 : 7 + s);
            mn.O = rec + (size_t)(T * C8 + C8 - 1) * HH;
            mn.sob = (int)LH; mn.soc = (int)CH8; mn.add = 1;
            mn.P = nullptr; mn.S = DST + (size_t)T * RC;
            mn.sab = HH; mn.sac = 32 * HH; mn.psA = (int)PS2;
            mn.ssb = HH; mn.ssc = 32 * HH; mn.psS = (int)PS2;
            mn.nrows = rows_; mn.ybeg = 0;
            D.g[0] = mn;
            if (s == 0) {           // + N128 ; M128 (M16 dead -> slot1)
                int yt = (rows_ + 127) / 128;
                int ng = 1;
                D.g[ng++] = g_sq(NA(10), MAs[0], NA(11), yt); yt += 8;
                D.g[ng++] = g_sq(MAs[0], NA(10), MAs[1], yt); yt += 8;
                launch(ng, yt);
            } else if (s == 1) {    // + N256
                int yt = (rows_ + 127) / 128;
                int ng = 1;
                D.g[ng++] = g_sq(NA(11), MAs[1], NA(12), yt); yt += 8;
                launch(ng, yt);
            } else {                // rider-less tails: BM=64 for fill
                launch64(1, (rows_ + 63) / 64);
            }
            copy_splits<<<T * 32, 256, 0, stream>>>(SRC, DST, PS2);
            short* t = SRC; SRC = DST; DST = t;
        }
        short* SFIN = SRC;   // true chunk-end splits (chunk 63 = rows 2016..2047)
        short* SFREE = DST;

        // ---- stage3 (7 groups x 2016 rows) + pred P1..8 (8 groups) in ONE launch
        for (int g = 0; g < 7; ++g) {
            GDv v{};
            v.A = SFIN; v.B = NA(g);
            v.O = nullptr; v.S = nullptr;
            v.P = rec + (size_t)(C8 + g) * HH;
            v.spb = (int)LH; v.spc = (int)CH8;
            v.sab = HH; v.sac = 32 * HH; v.psA = (int)PS2;
            v.nrows = 2016; v.ybeg = g * 16;
            D.g[g] = v;
        }
        for (int g = 7; g < 15; ++g) {
            int k = g - 7;           // P_{k+1}
            GDv v{};
            v.A = SFIN + 63 * RC; v.B = NA(k);
            v.O = outp + (size_t)k * HH; v.sob = (int)PB; v.soc = 0; v.add = 0;
            v.P = nullptr;
            v.S = SFREE + (size_t)k * RC; v.ssb = HH; v.ssc = 0; v.psS = (int)PS2;
            v.sab = HH; v.sac = 0; v.psA = (int)PS2;
            v.nrows = 32; v.ybeg = 112 + k;
            D.g[g] = v;
        }
        launch(15, 120);

        // ---- pred tail: ·M^8 then ·M^16 (sequential on SFREE splits)
        {
            GDv v{};
            v.A = SFREE; v.B = NA(7);
            v.O = outp + 8 * HH; v.sob = (int)PB; v.soc = HH; v.add = 0;
            v.P = nullptr;
            v.S = SFREE + 8 * RC; v.ssb = HH; v.ssc = 32 * HH; v.psS = (int)PS2;
            v.sab = HH; v.sac = 32 * HH; v.psA = (int)PS2;
            v.nrows = 256; v.ybeg = 0;
            D.g[0] = v;
            launch(1, 2);
            v.B = NA(8);
            v.O = outp + 16 * HH;
            v.S = nullptr;
            v.nrows = 512;
            D.g[0] = v;
            launch(1, 4);
        }

        ln_k<<<BB * PRED, 256, 0, stream>>>(outp, ln_w, ln_b);
        return;
    }

    // ================= fallback: proven R8 64-MiB tier =================
    {
        float* TP   = (float*)(wsb);
        short* SAP  = (short*)(wsb + 4 * MiB);
        short* SA0  = (short*)(wsb + 10 * MiB);
        short* SA1  = (short*)(wsb + 22 * MiB);
        short* SBM  = (short*)(wsb + 34 * MiB);
        short* SB8  = (short*)(wsb + 40 * MiB);
        short* SB16 = (short*)(wsb + 46 * MiB);
        short* SBr0 = (short*)(wsb + 52 * MiB);
        short* SBr1 = (short*)(wsb + 58 * MiB);

        transpose_k<<<dim3(32, 32), dim3(32, 8), 0, stream>>>(Whh, TP);
        split_a<<<dim3(1, HH), 256, 0, stream>>>(Wxh, RS, RC, SBr0, RS, RC, HM);
        gemm_mx<<<dim3(16, 128), 256, 0, stream>>>(x, SBr0, rec);
        split_a<<<dim3(1, HH), 256, 0, stream>>>(TP, RS, RC, SAP, RS, RC, HM);
        split_t<<<dim3(32, 32), dim3(32, 8), 0, stream>>>(TP, SBM);

        #define SQ64(SAi, SBi, Sot) \
            step_p64<<<dim3(16, 16), 256, 0, stream>>>(SAi, RS, RC, HM, SBi, \
                TP, RS, RC, 0, nulf, 0, 0, Sot, RS, RC, HM, 1024)
        SQ64(SAP, SBM, SA1);
        split_t<<<dim3(32, 32), dim3(32, 8), 0, stream>>>(TP, SBr0);
        SQ64(SA1, SBr0, SAP);
        split_t<<<dim3(32, 32), dim3(32, 8), 0, stream>>>(TP, SBr1);
        SQ64(SAP, SBr1, SA1);
        split_t<<<dim3(32, 32), dim3(32, 8), 0, stream>>>(TP, SB8);
        SQ64(SA1, SB8, SAP);
        split_t<<<dim3(32, 32), dim3(32, 8), 0, stream>>>(TP, SB16);

        split_a<<<dim3(1, 2048), 256, 0, stream>>>(rec, LH, CH8, SA0, RS, RC, PS2);
        for (int o = 1; o < C8; ++o) {
            short* Ain = (o & 1) ? SA0 : SA1;
            short* Sot = (o & 1) ? SA1 : SA0;
            step_p128<<<dim3(16, 16), 512, 0, stream>>>(Ain, RS, RC, PS2, SBM,
                rec + (size_t)o * HH, LH, CH8, 1, nulf, 0, 0,
                Sot, RS, RC, PS2, 2048);
        }
        #define SCAN(SRC, DST, T, SBpow) do { \
            int rows_ = (NC8 - (T)) * 32; \
            step_p128<<<dim3(16, (rows_ + 127) / 128), 512, 0, stream>>>( \
                SRC, RS, RC, PS2, SBpow, \
                rec + (size_t)((T) * C8 + C8 - 1) * HH, LH, CH8, 1, \
                nulf, 0, 0, DST + (size_t)(T) * RC, RS, RC, PS2, rows_); \
            copy_splits<<<(T) * 32, 256, 0, stream>>>(SRC, DST, PS2); \
        } while (0)
        #define SQI(SBi, SBo, last) do { \
            step_p64<<<dim3(16, 16), 256, 0, stream>>>(SAP, RS, RC, HM, SBi, \
                TP, RS, RC, 0, nulf, 0, 0, nuls, 0, 0, HM, 1024); \
            split_t<<<dim3(32, 32), dim3(32, 8), 0, stream>>>(TP, SBo); \
            if (!(last)) split_a<<<dim3(1, HH), 256, 0, stream>>>(TP, RS, RC, SAP, RS, RC, HM); \
        } while (0)
        SCAN(SA1, SA0, 1, SB8);
        SQI(SB16, SBr0, 0);
        SCAN(SA0, SA1, 2, SB16);
        SQI(SBr0, SBr1, 0);
        SCAN(SA1, SA0, 4, SBr0);
        SQI(SBr1, SBr0, 0);
        SCAN(SA0, SA1, 8, SBr1);
        SQI(SBr0, SBr1, 1);
        SCAN(SA1, SA0, 16, SBr0);
        SCAN(SA0, SA1, 32, SBr1);
        for (int o = 0; o < C8 - 1; ++o) {
            short* Ain = (o & 1) ? SA0 : SA1;
            short* Sot = (o & 1) ? SA1 : SA0;
            step_p128<<<dim3(16, 16), 512, 0, stream>>>(Ain, RS, RC, PS2, SBM,
                nulf, 0, 0, 0,
                rec + (size_t)(C8 + o) * HH, LH, CH8,
                (o == C8 - 2) ? nuls : Sot, RS, RC, PS2, 2016);
        }
        step_p<<<dim3(16, 1), 128, 0, stream>>>(SA1 + 63 * RC, RS, 0, PS2, SBM,
            outp, PB, 0, 0, nulf, 0, 0, SA0, RS, 0, PS2);
        step_p<<<dim3(16, 1), 128, 0, stream>>>(SA0, RS, 0, PS2, SBM,
            outp + HH, PB, 0, 0, nulf, 0, 0, SA0 + RC, RS, 0, PS2);
        tr_splits<<<dim3(32, 32, 3), dim3(32, 8), 0, stream>>>(SBM, SAP);
        SQ64(SAP, SBM, nuls);
        split_t<<<dim3(32, 32), dim3(32, 8), 0, stream>>>(TP, SBr0);
        step_p<<<dim3(16, 2), 128, 0, stream>>>(SA0, RS, RC, PS2, SBr0,
            outp + 2 * HH, PB, RS, 0, nulf, 0, 0,
            SA0 + 2 * RC, RS, RC, PS2);
        split_a<<<dim3(1, HH), 256, 0, stream>>>(TP, RS, RC, SAP, RS, RC, HM);
        SQ64(SAP, SBr0, nuls);
        split_t<<<dim3(32, 32), dim3(32, 8), 0, stream>>>(TP, SBr1);
        step_p<<<dim3(16, 4), 128, 0, stream>>>(SA0, RS, RC, PS2, SBr1,
            outp + 4 * HH, PB, RS, 0, nulf, 0, 0,
            SA0 + 4 * RC, RS, RC, PS2);
        step_p<<<dim3(16, 8), 128, 0, stream>>>(SA0, RS, RC, PS2, SB8,
            outp + 8 * HH, PB, RS, 0, nulf, 0, 0,
            SA0 + 8 * RC, RS, RC, PS2);
        step_p64<<<dim3(16, 8), 256, 0, stream>>>(SA0, RS, RC, PS2, SB16,
            outp + 16 * HH, PB, RS, 0, nulf, 0, 0,
            nuls, 0, 0, PS2, 512);
        #undef SQ64
        #undef SCAN
        #undef SQI

        ln_k<<<BB * PRED, 256, 0, stream>>>(outp, ln_w, ln_b);
    }
}

// Round 13
// 1263.901 us; speedup vs baseline: 1.2440x; 1.0004x over previous
//
#include <hip/hip_runtime.h>

#define BB 32
#define LL 512
#define HH 1024
#define PRED 32
#define C8 8             // chunk length
#define NC8 (LL / C8)    // 64 chunks
#define LN_EPS 1e-5f

typedef short bf16x8 __attribute__((ext_vector_type(8)));
typedef short s16x4  __attribute__((ext_vector_type(4)));
typedef float f32x4  __attribute__((ext_vector_type(4)));

static __device__ __forceinline__ void split3(float x, short& h, short& m, short& l) {
    unsigned u = __float_as_uint(x);
    unsigned rh = (u + 0x7fffu + ((u >> 16) & 1u)) & 0xffff0000u;
    h = (short)(rh >> 16);
    float x1 = x - __uint_as_float(rh);
    unsigned u1 = __float_as_uint(x1);
    unsigned rm = (u1 + 0x7fffu + ((u1 >> 16) & 1u)) & 0xffff0000u;
    m = (short)(rm >> 16);
    float x2 = x1 - __uint_as_float(rm);
    unsigned u2 = __float_as_uint(x2);
    unsigned rl = (u2 + 0x7fffu + ((u2 >> 16) & 1u)) & 0xffff0000u;
    l = (short)(rl >> 16);
}

static __device__ __forceinline__ void split2(float x, short& h, short& m) {
    unsigned u = __float_as_uint(x);
    unsigned rh = (u + 0x7fffu + ((u >> 16) & 1u)) & 0xffff0000u;
    h = (short)(rh >> 16);
    float x1 = x - __uint_as_float(rh);
    unsigned u1 = __float_as_uint(x1);
    unsigned rm = (u1 + 0x7fffu + ((u1 >> 16) & 1u)) & 0xffff0000u;
    m = (short)(rm >> 16);
}

#define MFMA6(ACC, AH, AM, AL, BH, BM, BL) \
    ACC = __builtin_amdgcn_mfma_f32_16x16x32_bf16(AL, BH, ACC, 0, 0, 0); \
    ACC = __builtin_amdgcn_mfma_f32_16x16x32_bf16(AH, BL, ACC, 0, 0, 0); \
    ACC = __builtin_amdgcn_mfma_f32_16x16x32_bf16(AM, BM, ACC, 0, 0, 0); \
    ACC = __builtin_amdgcn_mfma_f32_16x16x32_bf16(AM, BH, ACC, 0, 0, 0); \
    ACC = __builtin_amdgcn_mfma_f32_16x16x32_bf16(AH, BM, ACC, 0, 0, 0); \
    ACC = __builtin_amdgcn_mfma_f32_16x16x32_bf16(AH, BH, ACC, 0, 0, 0);

// ---------------------------------------------------------------------------
__global__ __launch_bounds__(256) void transpose_k(const float* __restrict__ in,
                                                   float* __restrict__ out) {
    __shared__ float tile[32][33];
    int bx = blockIdx.x * 32, by = blockIdx.y * 32;
    int tx = threadIdx.x, ty = threadIdx.y;
    #pragma unroll
    for (int i = 0; i < 32; i += 8)
        tile[ty + i][tx] = in[(size_t)(by + ty + i) * HH + bx + tx];
    __syncthreads();
    #pragma unroll
    for (int i = 0; i < 32; i += 8)
        out[(size_t)(bx + ty + i) * HH + by + tx] = tile[tx][ty + i];
}

// ---------------------------------------------------------------------------
__global__ __launch_bounds__(256) void split_a(const float* __restrict__ src, long sb, long sc,
                                               short* __restrict__ dst, long dsb, long dsc,
                                               long ps) {
    int r = blockIdx.y;
    const float* s = src + (long)(r & 31) * sb + (long)(r >> 5) * sc + threadIdx.x * 4;
    short* d = dst + (long)(r & 31) * dsb + (long)(r >> 5) * dsc + threadIdx.x * 4;
    float4 v = *(const float4*)s;
    float xs[4] = {v.x, v.y, v.z, v.w};
    s16x4 vh, vm, vl;
    #pragma unroll
    for (int j = 0; j < 4; ++j) {
        short h, m, l;
        split3(xs[j], h, m, l);
        vh[j] = h; vm[j] = m; vl[j] = l;
    }
    *(s16x4*)(d) = vh;
    *(s16x4*)(d + ps) = vm;
    *(s16x4*)(d + 2 * ps) = vl;
}

// ---------------------------------------------------------------------------
__global__ __launch_bounds__(256) void split_t(const float* __restrict__ in,
                                               short* __restrict__ out) {
    const size_t HM = (size_t)HH * HH;
    __shared__ float tile[32][33];
    int n0 = blockIdx.x * 32, k0 = blockIdx.y * 32;
    int tx = threadIdx.x, ty = threadIdx.y;
    #pragma unroll
    for (int i = 0; i < 32; i += 8)
        tile[ty + i][tx] = in[(size_t)(k0 + ty + i) * HH + n0 + tx];
    __syncthreads();
    #pragma unroll
    for (int i = 0; i < 32; i += 8) {
        float v = tile[tx][ty + i];
        short h, m, l;
        split3(v, h, m, l);
        size_t o = (size_t)(n0 + ty + i) * HH + k0 + tx;
        out[o] = h; out[HM + o] = m; out[2 * HM + o] = l;
    }
}

// ---------------------------------------------------------------------------
__global__ __launch_bounds__(256) void tr_splits(const short* __restrict__ in,
                                                 short* __restrict__ out) {
    const size_t HM = (size_t)HH * HH;
    __shared__ short tile[32][33];
    int p = blockIdx.z;
    int k0 = blockIdx.x * 32, n0 = blockIdx.y * 32;
    int tx = threadIdx.x, ty = threadIdx.y;
    #pragma unroll
    for (int i = 0; i < 32; i += 8)
        tile[ty + i][tx] = in[p * HM + (size_t)(n0 + ty + i) * HH + k0 + tx];
    __syncthreads();
    #pragma unroll
    for (int i = 0; i < 32; i += 8)
        out[p * HM + (size_t)(k0 + ty + i) * HH + n0 + tx] = tile[tx][ty + i];
}

// ---------------------------------------------------------------------------
__global__ __launch_bounds__(256) void copy_splits(const short* __restrict__ src,
                                                   short* __restrict__ dst, long ps) {
    size_t off = (size_t)blockIdx.x * HH + threadIdx.x * 4;
    *(s16x4*)(dst + off)          = *(const s16x4*)(src + off);
    *(s16x4*)(dst + ps + off)     = *(const s16x4*)(src + ps + off);
    *(s16x4*)(dst + 2 * ps + off) = *(const s16x4*)(src + 2 * ps + off);
}

// ---------------------------------------------------------------------------
// gemm_mx: 128x64 tile, bf16 2x2 split (proven R7). Optional SOUT: rows with
// (l&7)==0 additionally write their 3-plane split to SOUT (stage1 seed),
// dest row = b + 32*(l>>3), layout [row][k] linear, plane stride psS.
// ---------------------------------------------------------------------------
__global__ __launch_bounds__(256) void gemm_mx(const float* __restrict__ A,
                                               const short* __restrict__ SB,
                                               float* __restrict__ C,
                                               short* __restrict__ SOUT, long psS) {
    const size_t HM = (size_t)HH * HH;
    __shared__ __align__(16) short As2[2][128][40];
    __shared__ __align__(16) short Bs2[2][64][40];
    const int tid = threadIdx.x;
    const int lane = tid & 63;
    const int w = tid >> 6;
    const int n0 = blockIdx.x * 64;
    const int m0 = blockIdx.y * 128;
    const int ar = tid >> 1;
    const int akc = (tid & 1) * 16;
    const float* Arow = A + (size_t)(m0 + ar) * HH + akc;
    const int bp = tid >> 7;
    const int bnr = tid & 63;
    const int bkh = ((tid >> 6) & 1) * 16;
    const short* Brow = SB + bp * HM + (size_t)(n0 + bnr) * HH + bkh;
    const int fr = lane & 15;
    const int fk = (lane >> 4) * 8;

    f32x4 acc[2][4] = {};

    float4 av0 = *(const float4*)(Arow);
    float4 av1 = *(const float4*)(Arow + 4);
    float4 av2 = *(const float4*)(Arow + 8);
    float4 av3 = *(const float4*)(Arow + 12);
    bf16x8 rb0 = *(const bf16x8*)(Brow);
    bf16x8 rb1 = *(const bf16x8*)(Brow + 8);

    for (int kt = 0; kt < HH; kt += 32) {
        float xs[16] = {av0.x, av0.y, av0.z, av0.w, av1.x, av1.y, av1.z, av1.w,
                        av2.x, av2.y, av2.z, av2.w, av3.x, av3.y, av3.z, av3.w};
        bf16x8 vh0, vm0, vh1, vm1;
        #pragma unroll
        for (int j = 0; j < 8; ++j) {
            short h, m;
            split2(xs[j], h, m);
            vh0[j] = h; vm0[j] = m;
            split2(xs[j + 8], h, m);
            vh1[j] = h; vm1[j] = m;
        }
        *(bf16x8*)&As2[0][ar][akc]     = vh0;
        *(bf16x8*)&As2[0][ar][akc + 8] = vh1;
        *(bf16x8*)&As2[1][ar][akc]     = vm0;
        *(bf16x8*)&As2[1][ar][akc + 8] = vm1;
        *(bf16x8*)&Bs2[bp][bnr][bkh]     = rb0;
        *(bf16x8*)&Bs2[bp][bnr][bkh + 8] = rb1;
        __syncthreads();
        if (kt + 32 < HH) {
            const float* An = Arow + kt + 32;
            av0 = *(const float4*)(An);
            av1 = *(const float4*)(An + 4);
            av2 = *(const float4*)(An + 8);
            av3 = *(const float4*)(An + 12);
            const short* Bn = Brow + kt + 32;
            rb0 = *(const bf16x8*)(Bn);
            rb1 = *(const bf16x8*)(Bn + 8);
        }
        bf16x8 ah[2], am[2];
        #pragma unroll
        for (int i = 0; i < 2; ++i) {
            ah[i] = *(const bf16x8*)&As2[0][w * 32 + i * 16 + fr][fk];
            am[i] = *(const bf16x8*)&As2[1][w * 32 + i * 16 + fr][fk];
        }
        #pragma unroll
        for (int j = 0; j < 4; ++j) {
            bf16x8 bh = *(const bf16x8*)&Bs2[0][j * 16 + fr][fk];
            bf16x8 bm = *(const bf16x8*)&Bs2[1][j * 16 + fr][fk];
            #pragma unroll
            for (int i = 0; i < 2; ++i) {
                f32x4 a = acc[i][j];
                a = __builtin_amdgcn_mfma_f32_16x16x32_bf16(am[i], bm, a, 0, 0, 0);
                a = __builtin_amdgcn_mfma_f32_16x16x32_bf16(am[i], bh, a, 0, 0, 0);
                a = __builtin_amdgcn_mfma_f32_16x16x32_bf16(ah[i], bm, a, 0, 0, 0);
                a = __builtin_amdgcn_mfma_f32_16x16x32_bf16(ah[i], bh, a, 0, 0, 0);
                acc[i][j] = a;
            }
        }
        __syncthreads();
    }
    const int orow = (lane >> 4) * 4;
    #pragma unroll
    for (int i = 0; i < 2; ++i)
        #pragma unroll
        for (int j = 0; j < 4; ++j) {
            int c = n0 + j * 16 + fr;
            #pragma unroll
            for (int reg = 0; reg < 4; ++reg) {
                int r = m0 + w * 32 + i * 16 + orow + reg;
                float val = acc[i][j][reg];
                C[(size_t)r * HH + c] = val;
                if (SOUT) {
                    int l = r & (LL - 1);
                    if ((l & 7) == 0) {
                        int rr = (r >> 9) + 32 * (l >> 3);   // b + 32*chunk
                        short h, m, lo;
                        split3(val, h, m, lo);
                        short* s = SOUT + (size_t)rr * HH + c;
                        s[0] = h; s[psS] = m; s[2 * psS] = lo;
                    }
                }
            }
        }
}

// ---------------------------------------------------------------------------
// Descriptors for batched multi-group GEMMs.
// ---------------------------------------------------------------------------
struct GDv {
    const short* A; const short* B; float* O; float* P; short* S;
    int sab, sac, psA, sob, soc, spb, spc, ssb, ssc, psS, add, nrows, ybeg;
};
struct GDv16 { GDv g[16]; };

// ---------------------------------------------------------------------------
// step_g: batched bf16x6 MFMA GEMM, 128(M)x64(N), 4 waves (wave tile 32x64).
// Group with B==nullptr is a pure split-copy (A -> S) of its rows.
// ---------------------------------------------------------------------------
__global__ __launch_bounds__(256) void step_g(GDv16 dsc, int ng) {
    const size_t HM = (size_t)HH * HH;
    __shared__ __align__(16) short As[3][128][40];
    __shared__ __align__(16) short Bs[3][64][40];
    const int tid = threadIdx.x;
    const int lane = tid & 63;
    const int w = tid >> 6;
    const int yy = blockIdx.y;
    int gi = 0;
    for (int i = 1; i < ng; ++i)
        if (yy >= dsc.g[i].ybeg) gi = i;
    const GDv d = dsc.g[gi];
    const int n0 = blockIdx.x * 64;
    const int m0 = (yy - d.ybeg) * 128;
    if (!d.B) {   // copy group: whole block, no sync hazard
        int r = m0 + (tid >> 1);
        if (r < d.nrows) {
            int co = n0 + (tid & 1) * 32;
            const short* src = d.A + (long)(r & 31) * d.sab + (long)(r >> 5) * d.sac + co;
            short* dst = d.S + (long)(r & 31) * d.ssb + (long)(r >> 5) * d.ssc + co;
            #pragma unroll
            for (int p = 0; p < 3; ++p)
                #pragma unroll
                for (int jj = 0; jj < 8; ++jj)
                    *(s16x4*)(dst + p * (long)d.psS + jj * 4) =
                        *(const s16x4*)(src + p * (long)d.psA + jj * 4);
        }
        return;
    }
    const int ar = tid >> 1;
    const int akh = (tid & 1) * 16;
    const int agr = m0 + ar;
    const short* Arow = d.A + (long)(agr & 31) * d.sab + (long)(agr >> 5) * d.sac + akh;
    const int br = tid >> 2;
    const int bkc = (tid & 3) * 8;
    const short* Brow = d.B + (size_t)(n0 + br) * HH + bkc;
    const int fr = lane & 15;
    const int fk = (lane >> 4) * 8;
    const long psA = d.psA;

    f32x4 acc[2][4] = {};

    bf16x8 ra[6], rb[3];
    #pragma unroll
    for (int p = 0; p < 3; ++p) {
        ra[2 * p]     = *(const bf16x8*)(Arow + p * psA);
        ra[2 * p + 1] = *(const bf16x8*)(Arow + p * psA + 8);
        rb[p]         = *(const bf16x8*)(Brow + p * HM);
    }
    for (int kt = 0; kt < HH; kt += 32) {
        #pragma unroll
        for (int p = 0; p < 3; ++p) {
            *(bf16x8*)&As[p][ar][akh]     = ra[2 * p];
            *(bf16x8*)&As[p][ar][akh + 8] = ra[2 * p + 1];
            *(bf16x8*)&Bs[p][br][bkc]     = rb[p];
        }
        __syncthreads();
        if (kt + 32 < HH) {
            #pragma unroll
            for (int p = 0; p < 3; ++p) {
                ra[2 * p]     = *(const bf16x8*)(Arow + p * psA + kt + 32);
                ra[2 * p + 1] = *(const bf16x8*)(Arow + p * psA + kt + 40);
                rb[p]         = *(const bf16x8*)(Brow + p * HM + kt + 32);
            }
        }
        bf16x8 af[3][2], bfr[3][4];
        #pragma unroll
        for (int p = 0; p < 3; ++p) {
            #pragma unroll
            for (int mf = 0; mf < 2; ++mf)
                af[p][mf] = *(const bf16x8*)&As[p][w * 32 + mf * 16 + fr][fk];
            #pragma unroll
            for (int nf = 0; nf < 4; ++nf)
                bfr[p][nf] = *(const bf16x8*)&Bs[p][nf * 16 + fr][fk];
        }
        #pragma unroll
        for (int mf = 0; mf < 2; ++mf)
            #pragma unroll
            for (int nf = 0; nf < 4; ++nf) {
                MFMA6(acc[mf][nf], af[0][mf], af[1][mf], af[2][mf],
                      bfr[0][nf], bfr[1][nf], bfr[2][nf])
            }
        __syncthreads();
    }
    const int orow = (lane >> 4) * 4;
    #pragma unroll
    for (int mf = 0; mf < 2; ++mf)
        #pragma unroll
        for (int nf = 0; nf < 4; ++nf) {
            int c = n0 + nf * 16 + fr;
            #pragma unroll
            for (int reg = 0; reg < 4; ++reg) {
                int r = m0 + w * 32 + mf * 16 + orow + reg;
                if (r >= d.nrows) continue;
                long rb_ = (long)(r & 31), rc_ = (long)(r >> 5);
                float val = acc[mf][nf][reg];
                if (d.O) {
                    float* p = d.O + rb_ * d.sob + rc_ * d.soc + c;
                    if (d.add) val += *p;
                    *p = val;
                }
                if (d.P) {
                    float* q = d.P + rb_ * d.spb + rc_ * d.spc + c;
                    *q += val;
                }
                if (d.S) {
                    short h, m, l;
                    split3(val, h, m, l);
                    short* s = d.S + rb_ * d.ssb + rc_ * d.ssc + c;
                    s[0] = h; s[d.psS] = m; s[2 * (long)d.psS] = l;
                }
            }
        }
}

// ---------------------------------------------------------------------------
// step_g64: batched bf16x6 MFMA GEMM, 64(M)x64(N), 4 waves (2x2). Copy-group
// support identical to step_g (B==nullptr).
// ---------------------------------------------------------------------------
__global__ __launch_bounds__(256) void step_g64(GDv16 dsc, int ng) {
    const size_t HM = (size_t)HH * HH;
    __shared__ __align__(16) short As[3][64][40];
    __shared__ __align__(16) short Bs[3][64][40];
    const int tid = threadIdx.x;
    const int lane = tid & 63;
    const int w = tid >> 6;
    const int wr = w & 1;
    const int wc = w >> 1;
    const int yy = blockIdx.y;
    int gi = 0;
    for (int i = 1; i < ng; ++i)
        if (yy >= dsc.g[i].ybeg) gi = i;
    const GDv d = dsc.g[gi];
    const int n0 = blockIdx.x * 64;
    const int m0 = (yy - d.ybeg) * 64;
    if (!d.B) {   // copy group
        int r = m0 + (tid >> 2);
        if (r < d.nrows) {
            int co = n0 + (tid & 3) * 16;
            const short* src = d.A + (long)(r & 31) * d.sab + (long)(r >> 5) * d.sac + co;
            short* dst = d.S + (long)(r & 31) * d.ssb + (long)(r >> 5) * d.ssc + co;
            #pragma unroll
            for (int p = 0; p < 3; ++p)
                #pragma unroll
                for (int jj = 0; jj < 4; ++jj)
                    *(s16x4*)(dst + p * (long)d.psS + jj * 4) =
                        *(const s16x4*)(src + p * (long)d.psA + jj * 4);
        }
        return;
    }
    const int ar = tid >> 2;
    const int akc = (tid & 3) * 8;
    const int agr = m0 + ar;
    const short* Arow = d.A + (long)(agr & 31) * d.sab + (long)(agr >> 5) * d.sac + akc;
    const short* Brow = d.B + (size_t)(n0 + ar) * HH + akc;
    const int fr = lane & 15;
    const int fk = (lane >> 4) * 8;
    const long psA = d.psA;

    f32x4 acc00 = 0, acc01 = 0, acc10 = 0, acc11 = 0;

    bf16x8 ra0 = *(const bf16x8*)(Arow);
    bf16x8 ra1 = *(const bf16x8*)(Arow + psA);
    bf16x8 ra2 = *(const bf16x8*)(Arow + 2 * psA);
    bf16x8 rb0 = *(const bf16x8*)(Brow);
    bf16x8 rb1 = *(const bf16x8*)(Brow + HM);
    bf16x8 rb2 = *(const bf16x8*)(Brow + 2 * HM);

    for (int kt = 0; kt < HH; kt += 32) {
        *(bf16x8*)&As[0][ar][akc] = ra0;
        *(bf16x8*)&As[1][ar][akc] = ra1;
        *(bf16x8*)&As[2][ar][akc] = ra2;
        *(bf16x8*)&Bs[0][ar][akc] = rb0;
        *(bf16x8*)&Bs[1][ar][akc] = rb1;
        *(bf16x8*)&Bs[2][ar][akc] = rb2;
        __syncthreads();
        if (kt + 32 < HH) {
            const short* An = Arow + kt + 32;
            const short* Bn = Brow + kt + 32;
            ra0 = *(const bf16x8*)(An);
            ra1 = *(const bf16x8*)(An + psA);
            ra2 = *(const bf16x8*)(An + 2 * psA);
            rb0 = *(const bf16x8*)(Bn);
            rb1 = *(const bf16x8*)(Bn + HM);
            rb2 = *(const bf16x8*)(Bn + 2 * HM);
        }
        bf16x8 a00 = *(const bf16x8*)&As[0][wr * 32 + fr][fk];
        bf16x8 a01 = *(const bf16x8*)&As[0][wr * 32 + 16 + fr][fk];
        bf16x8 a10 = *(const bf16x8*)&As[1][wr * 32 + fr][fk];
        bf16x8 a11 = *(const bf16x8*)&As[1][wr * 32 + 16 + fr][fk];
        bf16x8 a20 = *(const bf16x8*)&As[2][wr * 32 + fr][fk];
        bf16x8 a21 = *(const bf16x8*)&As[2][wr * 32 + 16 + fr][fk];
        bf16x8 b00 = *(const bf16x8*)&Bs[0][wc * 32 + fr][fk];
        bf16x8 b01 = *(const bf16x8*)&Bs[0][wc * 32 + 16 + fr][fk];
        bf16x8 b10 = *(const bf16x8*)&Bs[1][wc * 32 + fr][fk];
        bf16x8 b11 = *(const bf16x8*)&Bs[1][wc * 32 + 16 + fr][fk];
        bf16x8 b20 = *(const bf16x8*)&Bs[2][wc * 32 + fr][fk];
        bf16x8 b21 = *(const bf16x8*)&Bs[2][wc * 32 + 16 + fr][fk];
        MFMA6(acc00, a00, a10, a20, b00, b10, b20)
        MFMA6(acc01, a00, a10, a20, b01, b11, b21)
        MFMA6(acc10, a01, a11, a21, b00, b10, b20)
        MFMA6(acc11, a01, a11, a21, b01, b11, b21)
        __syncthreads();
    }
    const int orow = (lane >> 4) * 4;
    #pragma unroll
    for (int mf = 0; mf < 2; ++mf) {
        #pragma unroll
        for (int nf = 0; nf < 2; ++nf) {
            f32x4 v = mf == 0 ? (nf == 0 ? acc00 : acc01) : (nf == 0 ? acc10 : acc11);
            int c = n0 + wc * 32 + nf * 16 + fr;
            #pragma unroll
            for (int reg = 0; reg < 4; ++reg) {
                int r = m0 + wr * 32 + mf * 16 + orow + reg;
                if (r >= d.nrows) continue;
                long rb = (long)(r & 31), rc = (long)(r >> 5);
                float val = v[reg];
                if (d.O) {
                    float* p = d.O + rb * d.sob + rc * d.soc + c;
                    if (d.add) val += *p;
                    *p = val;
                }
                if (d.P) { float* q = d.P + rb * d.spb + rc * d.spc + c; *q += val; }
                if (d.S) {
                    short h, m, l;
                    split3(val, h, m, l);
                    short* s = d.S + rb * d.ssb + rc * d.ssc + c;
                    s[0] = h; s[d.psS] = m; s[2 * (long)d.psS] = l;
                }
            }
        }
    }
}

// ---------------------------------------------------------------------------
// step_p / step_p64 / step_p128: proven kernels for the 64-MiB fallback.
// ---------------------------------------------------------------------------
__global__ __launch_bounds__(128) void step_p(
    const short* __restrict__ SA, long sab, long sac, long psA,
    const short* __restrict__ SB,
    float* __restrict__ O, long sob, long soc, int add,
    float* __restrict__ P, long spb, long spc,
    short* __restrict__ S, long ssb, long ssc, long psS) {
    const size_t HM = (size_t)HH * HH;
    __shared__ __align__(16) short As[3][32][40];
    __shared__ __align__(16) short Bs[3][64][40];
    const int tid = threadIdx.x;
    const int lane = tid & 63;
    const int w = tid >> 6;
    const int n0 = blockIdx.x * 64;
    const int m0 = blockIdx.y * 32;
    const int ar = tid >> 2;
    const int akc = (tid & 3) * 8;
    const int agr = m0 + ar;
    const short* Arow = SA + (long)(agr & 31) * sab + (long)(agr >> 5) * sac + akc;
    const int bnr = tid & 63;
    const int bkh = (tid >> 6) * 16;
    const short* Brow = SB + (size_t)(n0 + bnr) * HH + bkh;
    const int fr = lane & 15;
    const int fk = (lane >> 4) * 8;
    f32x4 acc00 = 0, acc01 = 0, acc10 = 0, acc11 = 0;
    bf16x8 ra0 = *(const bf16x8*)(Arow);
    bf16x8 ra1 = *(const bf16x8*)(Arow + psA);
    bf16x8 ra2 = *(const bf16x8*)(Arow + 2 * psA);
    bf16x8 rb0 = *(const bf16x8*)(Brow);
    bf16x8 rb1 = *(const bf16x8*)(Brow + 8);
    bf16x8 rb2 = *(const bf16x8*)(Brow + HM);
    bf16x8 rb3 = *(const bf16x8*)(Brow + HM + 8);
    bf16x8 rb4 = *(const bf16x8*)(Brow + 2 * HM);
    bf16x8 rb5 = *(const bf16x8*)(Brow + 2 * HM + 8);
    for (int kt = 0; kt < HH; kt += 32) {
        *(bf16x8*)&As[0][ar][akc] = ra0;
        *(bf16x8*)&As[1][ar][akc] = ra1;
        *(bf16x8*)&As[2][ar][akc] = ra2;
        *(bf16x8*)&Bs[0][bnr][bkh] = rb0;
        *(bf16x8*)&Bs[0][bnr][bkh + 8] = rb1;
        *(bf16x8*)&Bs[1][bnr][bkh] = rb2;
        *(bf16x8*)&Bs[1][bnr][bkh + 8] = rb3;
        *(bf16x8*)&Bs[2][bnr][bkh] = rb4;
        *(bf16x8*)&Bs[2][bnr][bkh + 8] = rb5;
        __syncthreads();
        if (kt + 32 < HH) {
            const short* An = Arow + kt + 32;
            const short* Bn = Brow + kt + 32;
            ra0 = *(const bf16x8*)(An);
            ra1 = *(const bf16x8*)(An + psA);
            ra2 = *(const bf16x8*)(An + 2 * psA);
            rb0 = *(const bf16x8*)(Bn);
            rb1 = *(const bf16x8*)(Bn + 8);
            rb2 = *(const bf16x8*)(Bn + HM);
            rb3 = *(const bf16x8*)(Bn + HM + 8);
            rb4 = *(const bf16x8*)(Bn + 2 * HM);
            rb5 = *(const bf16x8*)(Bn + 2 * HM + 8);
        }
        bf16x8 a00 = *(const bf16x8*)&As[0][fr][fk];
        bf16x8 a01 = *(const bf16x8*)&As[0][16 + fr][fk];
        bf16x8 a10 = *(const bf16x8*)&As[1][fr][fk];
        bf16x8 a11 = *(const bf16x8*)&As[1][16 + fr][fk];
        bf16x8 a20 = *(const bf16x8*)&As[2][fr][fk];
        bf16x8 a21 = *(const bf16x8*)&As[2][16 + fr][fk];
        bf16x8 b00 = *(const bf16x8*)&Bs[0][w * 32 + fr][fk];
        bf16x8 b01 = *(const bf16x8*)&Bs[0][w * 32 + 16 + fr][fk];
        bf16x8 b10 = *(const bf16x8*)&Bs[1][w * 32 + fr][fk];
        bf16x8 b11 = *(const bf16x8*)&Bs[1][w * 32 + 16 + fr][fk];
        bf16x8 b20 = *(const bf16x8*)&Bs[2][w * 32 + fr][fk];
        bf16x8 b21 = *(const bf16x8*)&Bs[2][w * 32 + 16 + fr][fk];
        MFMA6(acc00, a00, a10, a20, b00, b10, b20)
        MFMA6(acc01, a00, a10, a20, b01, b11, b21)
        MFMA6(acc10, a01, a11, a21, b00, b10, b20)
        MFMA6(acc11, a01, a11, a21, b01, b11, b21)
        __syncthreads();
    }
    const int orow = (lane >> 4) * 4;
    #pragma unroll
    for (int mf = 0; mf < 2; ++mf) {
        #pragma unroll
        for (int nf = 0; nf < 2; ++nf) {
            f32x4 v = mf == 0 ? (nf == 0 ? acc00 : acc01) : (nf == 0 ? acc10 : acc11);
            int c = n0 + w * 32 + nf * 16 + fr;
            #pragma unroll
            for (int reg = 0; reg < 4; ++reg) {
                int r = m0 + mf * 16 + orow + reg;
                long rb = (long)(r & 31), rc = (long)(r >> 5);
                float val = v[reg];
                if (O) {
                    float* p = O + rb * sob + rc * soc + c;
                    if (add) val += *p;
                    *p = val;
                }
                if (P) { float* q = P + rb * spb + rc * spc + c; *q += val; }
                if (S) {
                    short h, m, l;
                    split3(val, h, m, l);
                    short* s = S + rb * ssb + rc * ssc + c;
                    s[0] = h; s[psS] = m; s[2 * psS] = l;
                }
            }
        }
    }
}

__global__ __launch_bounds__(256) void step_p64(
    const short* __restrict__ SA, long sab, long sac, long psA,
    const short* __restrict__ SB,
    float* __restrict__ O, long sob, long soc, int add,
    float* __restrict__ P, long spb, long spc,
    short* __restrict__ S, long ssb, long ssc, long psS,
    int nrows) {
    const size_t HM = (size_t)HH * HH;
    __shared__ __align__(16) short As[3][64][40];
    __shared__ __align__(16) short Bs[3][64][40];
    const int tid = threadIdx.x;
    const int lane = tid & 63;
    const int w = tid >> 6;
    const int wr = w & 1;
    const int wc = w >> 1;
    const int n0 = blockIdx.x * 64;
    const int m0 = blockIdx.y * 64;
    const int ar = tid >> 2;
    const int akc = (tid & 3) * 8;
    const int agr = m0 + ar;
    const short* Arow = SA + (long)(agr & 31) * sab + (long)(agr >> 5) * sac + akc;
    const short* Brow = SB + (size_t)(n0 + ar) * HH + akc;
    const int fr = lane & 15;
    const int fk = (lane >> 4) * 8;
    f32x4 acc00 = 0, acc01 = 0, acc10 = 0, acc11 = 0;
    bf16x8 ra0 = *(const bf16x8*)(Arow);
    bf16x8 ra1 = *(const bf16x8*)(Arow + psA);
    bf16x8 ra2 = *(const bf16x8*)(Arow + 2 * psA);
    bf16x8 rb0 = *(const bf16x8*)(Brow);
    bf16x8 rb1 = *(const bf16x8*)(Brow + HM);
    bf16x8 rb2 = *(const bf16x8*)(Brow + 2 * HM);
    for (int kt = 0; kt < HH; kt += 32) {
        *(bf16x8*)&As[0][ar][akc] = ra0;
        *(bf16x8*)&As[1][ar][akc] = ra1;
        *(bf16x8*)&As[2][ar][akc] = ra2;
        *(bf16x8*)&Bs[0][ar][akc] = rb0;
        *(bf16x8*)&Bs[1][ar][akc] = rb1;
        *(bf16x8*)&Bs[2][ar][akc] = rb2;
        __syncthreads();
        if (kt + 32 < HH) {
            const short* An = Arow + kt + 32;
            const short* Bn = Brow + kt + 32;
            ra0 = *(const bf16x8*)(An);
            ra1 = *(const bf16x8*)(An + psA);
            ra2 = *(const bf16x8*)(An + 2 * psA);
            rb0 = *(const bf16x8*)(Bn);
            rb1 = *(const bf16x8*)(Bn + HM);
            rb2 = *(const bf16x8*)(Bn + 2 * HM);
        }
        bf16x8 a00 = *(const bf16x8*)&As[0][wr * 32 + fr][fk];
        bf16x8 a01 = *(const bf16x8*)&As[0][wr * 32 + 16 + fr][fk];
        bf16x8 a10 = *(const bf16x8*)&As[1][wr * 32 + fr][fk];
        bf16x8 a11 = *(const bf16x8*)&As[1][wr * 32 + 16 + fr][fk];
        bf16x8 a20 = *(const bf16x8*)&As[2][wr * 32 + fr][fk];
        bf16x8 a21 = *(const bf16x8*)&As[2][wr * 32 + 16 + fr][fk];
        bf16x8 b00 = *(const bf16x8*)&Bs[0][wc * 32 + fr][fk];
        bf16x8 b01 = *(const bf16x8*)&Bs[0][wc * 32 + 16 + fr][fk];
        bf16x8 b10 = *(const bf16x8*)&Bs[1][wc * 32 + fr][fk];
        bf16x8 b11 = *(const bf16x8*)&Bs[1][wc * 32 + 16 + fr][fk];
        bf16x8 b20 = *(const bf16x8*)&Bs[2][wc * 32 + fr][fk];
        bf16x8 b21 = *(const bf16x8*)&Bs[2][wc * 32 + 16 + fr][fk];
        MFMA6(acc00, a00, a10, a20, b00, b10, b20)
        MFMA6(acc01, a00, a10, a20, b01, b11, b21)
        MFMA6(acc10, a01, a11, a21, b00, b10, b20)
        MFMA6(acc11, a01, a11, a21, b01, b11, b21)
        __syncthreads();
    }
    const int orow = (lane >> 4) * 4;
    #pragma unroll
    for (int mf = 0; mf < 2; ++mf) {
        #pragma unroll
        for (int nf = 0; nf < 2; ++nf) {
            f32x4 v = mf == 0 ? (nf == 0 ? acc00 : acc01) : (nf == 0 ? acc10 : acc11);
            int c = n0 + wc * 32 + nf * 16 + fr;
            #pragma unroll
            for (int reg = 0; reg < 4; ++reg) {
                int r = m0 + wr * 32 + mf * 16 + orow + reg;
                if (r >= nrows) continue;
                long rb = (long)(r & 31), rc = (long)(r >> 5);
                float val = v[reg];
                if (O) {
                    float* p = O + rb * sob + rc * soc + c;
                    if (add) val += *p;
                    *p = val;
                }
                if (P) { float* q = P + rb * spb + rc * spc + c; *q += val; }
                if (S) {
                    short h, m, l;
                    split3(val, h, m, l);
                    short* s = S + rb * ssb + rc * ssc + c;
                    s[0] = h; s[psS] = m; s[2 * psS] = l;
                }
            }
        }
    }
}

__global__ __launch_bounds__(512) void step_p128(
    const short* __restrict__ SA, long sab, long sac, long psA,
    const short* __restrict__ SB,
    float* __restrict__ O, long sob, long soc, int add,
    float* __restrict__ P, long spb, long spc,
    short* __restrict__ S, long ssb, long ssc, long psS,
    int nrows) {
    const size_t HM = (size_t)HH * HH;
    __shared__ __align__(16) short As[3][128][40];
    __shared__ __align__(16) short Bs[3][64][40];
    const int tid = threadIdx.x;
    const int lane = tid & 63;
    const int w = tid >> 6;
    const int wr = w & 3;
    const int wc = w >> 2;
    const int n0 = blockIdx.x * 64;
    const int m0 = blockIdx.y * 128;
    const int ar = tid >> 2;
    const int akc = (tid & 3) * 8;
    const int agr = m0 + ar;
    const short* Arow = SA + (long)(agr & 31) * sab + (long)(agr >> 5) * sac + akc;
    const bool bst = (tid < 384);
    const int bp = (tid >> 7) == 3 ? 2 : (tid >> 7);
    const int bt = tid & 127;
    const int bnr = bt >> 1;
    const int bkh = (bt & 1) * 16;
    const short* Brow = SB + (size_t)bp * HM + (size_t)(n0 + bnr) * HH + bkh;
    const int fr = lane & 15;
    const int fk = (lane >> 4) * 8;
    f32x4 acc00 = 0, acc01 = 0, acc10 = 0, acc11 = 0;
    bf16x8 ra0 = *(const bf16x8*)(Arow);
    bf16x8 ra1 = *(const bf16x8*)(Arow + psA);
    bf16x8 ra2 = *(const bf16x8*)(Arow + 2 * psA);
    bf16x8 rb0 = {}, rb1 = {};
    if (bst) { rb0 = *(const bf16x8*)(Brow); rb1 = *(const bf16x8*)(Brow + 8); }
    for (int kt = 0; kt < HH; kt += 32) {
        *(bf16x8*)&As[0][ar][akc] = ra0;
        *(bf16x8*)&As[1][ar][akc] = ra1;
        *(bf16x8*)&As[2][ar][akc] = ra2;
        if (bst) {
            *(bf16x8*)&Bs[bp][bnr][bkh]     = rb0;
            *(bf16x8*)&Bs[bp][bnr][bkh + 8] = rb1;
        }
        __syncthreads();
        if (kt + 32 < HH) {
            const short* An = Arow + kt + 32;
            ra0 = *(const bf16x8*)(An);
            ra1 = *(const bf16x8*)(An + psA);
            ra2 = *(const bf16x8*)(An + 2 * psA);
            if (bst) {
                const short* Bn = Brow + kt + 32;
                rb0 = *(const bf16x8*)(Bn);
                rb1 = *(const bf16x8*)(Bn + 8);
            }
        }
        bf16x8 a00 = *(const bf16x8*)&As[0][wr * 32 + fr][fk];
        bf16x8 a01 = *(const bf16x8*)&As[0][wr * 32 + 16 + fr][fk];
        bf16x8 a10 = *(const bf16x8*)&As[1][wr * 32 + fr][fk];
        bf16x8 a11 = *(const bf16x8*)&As[1][wr * 32 + 16 + fr][fk];
        bf16x8 a20 = *(const bf16x8*)&As[2][wr * 32 + fr][fk];
        bf16x8 a21 = *(const bf16x8*)&As[2][wr * 32 + 16 + fr][fk];
        bf16x8 b00 = *(const bf16x8*)&Bs[0][wc * 32 + fr][fk];
        bf16x8 b01 = *(const bf16x8*)&Bs[0][wc * 32 + 16 + fr][fk];
        bf16x8 b10 = *(const bf16x8*)&Bs[1][wc * 32 + fr][fk];
        bf16x8 b11 = *(const bf16x8*)&Bs[1][wc * 32 + 16 + fr][fk];
        bf16x8 b20 = *(const bf16x8*)&Bs[2][wc * 32 + fr][fk];
        bf16x8 b21 = *(const bf16x8*)&Bs[2][wc * 32 + 16 + fr][fk];
        MFMA6(acc00, a00, a10, a20, b00, b10, b20)
        MFMA6(acc01, a00, a10, a20, b01, b11, b21)
        MFMA6(acc10, a01, a11, a21, b00, b10, b20)
        MFMA6(acc11, a01, a11, a21, b01, b11, b21)
        __syncthreads();
    }
    const int orow = (lane >> 4) * 4;
    #pragma unroll
    for (int mf = 0; mf < 2; ++mf) {
        #pragma unroll
        for (int nf = 0; nf < 2; ++nf) {
            f32x4 v = mf == 0 ? (nf == 0 ? acc00 : acc01) : (nf == 0 ? acc10 : acc11);
            int c = n0 + wc * 32 + nf * 16 + fr;
            #pragma unroll
            for (int reg = 0; reg < 4; ++reg) {
                int r = m0 + wr * 32 + mf * 16 + orow + reg;
                if (r >= nrows) continue;
                long rb = (long)(r & 31), rc = (long)(r >> 5);
                float val = v[reg];
                if (O) {
                    float* p = O + rb * sob + rc * soc + c;
                    if (add) val += *p;
                    *p = val;
                }
                if (P) { float* q = P + rb * spb + rc * spc + c; *q += val; }
                if (S) {
                    short h, m, l;
                    split3(val, h, m, l);
                    short* s = S + rb * ssb + rc * ssc + c;
                    s[0] = h; s[psS] = m; s[2 * psS] = l;
                }
            }
        }
    }
}

// ---------------------------------------------------------------------------
__global__ __launch_bounds__(256) void ln_k(float* __restrict__ y,
                                            const float* __restrict__ w,
                                            const float* __restrict__ bia) {
    __shared__ float red[8];
    int row = blockIdx.x;
    float* p = y + (size_t)row * HH;
    int i4 = threadIdx.x * 4;
    float4 v = *(const float4*)&p[i4];
    float s = v.x + v.y + v.z + v.w;
    #pragma unroll
    for (int o = 32; o > 0; o >>= 1) s += __shfl_down(s, o, 64);
    int wid = threadIdx.x >> 6;
    if ((threadIdx.x & 63) == 0) red[wid] = s;
    __syncthreads();
    if (threadIdx.x == 0) red[4] = (red[0] + red[1] + red[2] + red[3]) * (1.f / HH);
    __syncthreads();
    float mu = red[4];
    float dx = v.x - mu, dy = v.y - mu, dz = v.z - mu, dw = v.w - mu;
    float q = dx * dx + dy * dy + dz * dz + dw * dw;
    #pragma unroll
    for (int o = 32; o > 0; o >>= 1) q += __shfl_down(q, o, 64);
    if ((threadIdx.x & 63) == 0) red[wid] = q;
    __syncthreads();
    if (threadIdx.x == 0) red[5] = (red[0] + red[1] + red[2] + red[3]) * (1.f / HH);
    __syncthreads();
    float rs = rsqrtf(red[5] + LN_EPS);
    float4 o4;
    o4.x = dx * rs * w[i4 + 0] + bia[i4 + 0];
    o4.y = dy * rs * w[i4 + 1] + bia[i4 + 1];
    o4.z = dz * rs * w[i4 + 2] + bia[i4 + 2];
    o4.w = dw * rs * w[i4 + 3] + bia[i4 + 3];
    *(float4*)&p[i4] = o4;
}

// ---------------------------------------------------------------------------
extern "C" void kernel_launch(void* const* d_in, const int* in_sizes, int n_in,
                              void* d_out, int out_size, void* d_ws, size_t ws_size,
                              hipStream_t stream) {
    const float* x    = (const float*)d_in[0];
    const float* Wxh  = (const float*)d_in[1];
    const float* Whh  = (const float*)d_in[2];
    const float* ln_w = (const float*)d_in[3];
    const float* ln_b = (const float*)d_in[4];

    const size_t MiB = 1024 * 1024;
    const long HM  = (long)HH * HH;
    const long PS2 = 2048L * HH;
    float* rec  = (float*)d_out;
    float* outp = rec + (size_t)BB * LL * HH;

    const long LH  = (long)LL * HH;
    const long CH8 = (long)C8 * HH;
    const long PB  = (long)PRED * HH;
    const long RS  = (long)HH;
    const long RC  = 32L * HH;
    float* nulf = (float*)nullptr;
    short* nuls = (short*)nullptr;
    char* wsb = (char*)d_ws;

    if (ws_size >= 124 * MiB) {
        // ======== tier A: R12 structure + folded copies + fused seed ========
        auto NA = [&](int idx) -> short* { return (short*)wsb + (size_t)idx * 3 * HM; };
        short* MAs[3] = {(short*)(wsb + 78 * MiB), (short*)(wsb + 84 * MiB),
                         (short*)(wsb + 90 * MiB)};
        short* SA0 = (short*)(wsb + 96 * MiB);    // 12 MiB (2048-row splits)
        short* SA1 = (short*)(wsb + 108 * MiB);   // 12 MiB
        short* SBW = SA1;                         // alias, consumed before SA1 live
        float* TPf = (float*)(wsb + 114 * MiB);   // 4 MiB, inside SA1 upper half

        GDv16 D{};
        auto launch = [&](int ng, int ytot) {
            step_g<<<dim3(16, ytot), 256, 0, stream>>>(D, ng);
        };
        auto launch64 = [&](int ng, int ytot) {
            step_g64<<<dim3(16, ytot), 256, 0, stream>>>(D, ng);
        };
        auto g_sq = [&](const short* A_, const short* B_, short* S_, int ybeg) -> GDv {
            GDv v{};
            v.A = A_; v.B = B_; v.O = nullptr; v.P = nullptr; v.S = S_;
            v.sab = HH; v.sac = 32 * HH; v.psA = (int)HM;
            v.ssb = HH; v.ssc = 32 * HH; v.psS = (int)HM;
            v.add = 0; v.nrows = 1024; v.ybeg = ybeg;
            return v;
        };
        auto g_cp = [&](const short* A_, short* S_, int nrows, int ybeg) -> GDv {
            GDv v{};
            v.A = A_; v.B = nullptr; v.O = nullptr; v.P = nullptr; v.S = S_;
            v.sab = HH; v.sac = 32 * HH; v.psA = (int)PS2;
            v.ssb = HH; v.ssc = 32 * HH; v.psS = (int)PS2;
            v.add = 0; v.nrows = nrows; v.ybeg = ybeg;
            return v;
        };

        // ---- seeds: NA1 = splits(Whh), MA1 = splits(Whh^T), SBW = splits(Wxh)
        transpose_k<<<dim3(32, 32), dim3(32, 8), 0, stream>>>(Whh, TPf);
        split_a<<<dim3(1, HH), 256, 0, stream>>>(Whh, RS, RC, NA(0), RS, RC, HM);
        split_a<<<dim3(1, HH), 256, 0, stream>>>(TPf, RS, RC, MAs[0], RS, RC, HM);
        split_a<<<dim3(1, HH), 256, 0, stream>>>(Wxh, RS, RC, SBW, RS, RC, HM);
        // gemm also emits stage1 seed splits (chunk-start rows) into SA0
        gemm_mx<<<dim3(16, 128), 256, 0, stream>>>(x, SBW, rec, SA0, PS2);

        // ---- stage1 (7 sequential steps of 2048 rows) + carried power groups
        short* SAc = SA0;
        short* SAn = SA1;
        for (int o = 1; o < C8; ++o) {
            GDv mn{};
            mn.A = SAc; mn.B = NA(0);
            mn.O = rec + (size_t)o * HH; mn.sob = (int)LH; mn.soc = (int)CH8; mn.add = 1;
            mn.P = nullptr; mn.S = SAn;
            mn.sab = HH; mn.sac = 32 * HH; mn.psA = (int)PS2;
            mn.ssb = HH; mn.ssc = 32 * HH; mn.psS = (int)PS2;
            mn.nrows = 2048; mn.ybeg = 0;
            D.g[0] = mn;
            int ng = 1, yt = 16;
            auto add_sq = [&](const short* A_, const short* B_, short* S_) {
                D.g[ng++] = g_sq(A_, B_, S_, yt); yt += 8;
            };
            switch (o) {
                case 1:  // M2 = M·M ; N2 = N·N
                    add_sq(MAs[0], NA(0), MAs[1]);
                    add_sq(NA(0), MAs[0], NA(1));
                    break;
                case 2:  // M4 ; N3 ; N4
                    add_sq(MAs[1], NA(1), MAs[2]);
                    add_sq(NA(1), MAs[0], NA(2));
                    add_sq(NA(1), MAs[1], NA(3));
                    break;
                case 3:  // N5 ; N6 ; N8
                    add_sq(NA(3), MAs[0], NA(4));
                    add_sq(NA(3), MAs[1], NA(5));
                    add_sq(NA(3), MAs[2], NA(7));
                    break;
                case 4:  // N7 ; M8 (MA1 dead -> slot0)
                    add_sq(NA(2), MAs[2], NA(6));
                    add_sq(MAs[2], NA(3), MAs[0]);
                    break;
                case 5:  // N16 ; M16 (MA2 dead -> slot1)
                    add_sq(NA(7), MAs[0], NA(8));
                    add_sq(MAs[0], NA(7), MAs[1]);
                    break;
                case 6:  // N32 ; M32 (MA4 dead -> slot2)
                    add_sq(NA(8), MAs[1], NA(9));
                    add_sq(MAs[1], NA(8), MAs[2]);
                    break;
                case 7:  // N64 ; M64 (M8 dead -> slot0)
                    add_sq(NA(9), MAs[2], NA(10));
                    add_sq(MAs[2], NA(9), MAs[0]);
                    break;
            }
            launch(ng, yt);
            short* t = SAc; SAc = SAn; SAn = t;
        }
        // chunk-end splits now in SAc (= SA1)

        // ---- Hillis-Steele scan over 64 chunk-ends
        // s=0,1 carry power riders (step_g, BM=128); s=2..5 use step_g64 (BM=64).
        // Prefix copy rides each launch as a B==nullptr group.
        short* SRC = SAc;
        short* DST = SAn;
        for (int s = 0; s < 6; ++s) {
            int T = 1 << s;
            int rows_ = (NC8 - T) * 32;
            GDv mn{};
            mn.A = SRC; mn.B = NA(s == 0 ? 7 : 7 + s);
            mn.O = rec + (size_t)(T * C8 + C8 - 1) * HH;
            mn.sob = (int)LH; mn.soc = (int)CH8; mn.add = 1;
            mn.P = nullptr; mn.S = DST + (size_t)T * RC;
            mn.sab = HH; mn.sac = 32 * HH; mn.psA = (int)PS2;
            mn.ssb = HH; mn.ssc = 32 * HH; mn.psS = (int)PS2;
            mn.nrows = rows_; mn.ybeg = 0;
            D.g[0] = mn;
            if (s == 0) {           // + N128 ; M128 (M16 dead -> slot1) + copy
                int yt = (rows_ + 127) / 128;
                int ng = 1;
                D.g[ng++] = g_sq(NA(10), MAs[0], NA(11), yt); yt += 8;
                D.g[ng++] = g_sq(MAs[0], NA(10), MAs[1], yt); yt += 8;
                D.g[ng++] = g_cp(SRC, DST, T * 32, yt); yt += (T * 32 + 127) / 128;
                launch(ng, yt);
            } else if (s == 1) {    // + N256 + copy
                int yt = (rows_ + 127) / 128;
                int ng = 1;
                D.g[ng++] = g_sq(NA(11), MAs[1], NA(12), yt); yt += 8;
                D.g[ng++] = g_cp(SRC, DST, T * 32, yt); yt += (T * 32 + 127) / 128;
                launch(ng, yt);
            } else {                // rider-less tails: BM=64 + copy
                int yt = (rows_ + 63) / 64;
                int ng = 1;
                D.g[ng++] = g_cp(SRC, DST, T * 32, yt); yt += (T * 32 + 63) / 64;
                launch64(ng, yt);
            }
            short* t = SRC; SRC = DST; DST = t;
        }
        short* SFIN = SRC;   // true chunk-end splits (chunk 63 = rows 2016..2047)
        short* SFREE = DST;

        // ---- stage3 (7 groups x 2016 rows) + pred P1..8 (8 groups) in ONE launch
        for (int g = 0; g < 7; ++g) {
            GDv v{};
            v.A = SFIN; v.B = NA(g);
            v.O = nullptr; v.S = nullptr;
            v.P = rec + (size_t)(C8 + g) * HH;
            v.spb = (int)LH; v.spc = (int)CH8;
            v.sab = HH; v.sac = 32 * HH; v.psA = (int)PS2;
            v.nrows = 2016; v.ybeg = g * 16;
            D.g[g] = v;
        }
        for (int g = 7; g < 15; ++g) {
            int k = g - 7;           // P_{k+1}
            GDv v{};
            v.A = SFIN + 63 * RC; v.B = NA(k);
            v.O = outp + (size_t)k * HH; v.sob = (int)PB; v.soc = 0; v.add = 0;
            v.P = nullptr;
            v.S = SFREE + (size_t)k * RC; v.ssb = HH; v.ssc = 0; v.psS = (int)PS2;
            v.sab = HH; v.sac = 0; v.psA = (int)PS2;
            v.nrows = 32; v.ybeg = 112 + k;
            D.g[g] = v;
        }
        launch(15, 120);

        // ---- pred tail: ·M^8 then ·M^16 (sequential on SFREE splits)
        {
            GDv v{};
            v.A = SFREE; v.B = NA(7);
            v.O = outp + 8 * HH; v.sob = (int)PB; v.soc = HH; v.add = 0;
            v.P = nullptr;
            v.S = SFREE + 8 * RC; v.ssb = HH; v.ssc = 32 * HH; v.psS = (int)PS2;
            v.sab = HH; v.sac = 32 * HH; v.psA = (int)PS2;
            v.nrows = 256; v.ybeg = 0;
            D.g[0] = v;
            launch(1, 2);
            v.B = NA(8);
            v.O = outp + 16 * HH;
            v.S = nullptr;
            v.nrows = 512;
            D.g[0] = v;
            launch(1, 4);
        }

        ln_k<<<BB * PRED, 256, 0, stream>>>(outp, ln_w, ln_b);
        return;
    }

    // ================= fallback: proven R8 64-MiB tier =================
    {
        float* TP   = (float*)(wsb);
        short* SAP  = (short*)(wsb + 4 * MiB);
        short* SA0  = (short*)(wsb + 10 * MiB);
        short* SA1  = (short*)(wsb + 22 * MiB);
        short* SBM  = (short*)(wsb + 34 * MiB);
        short* SB8  = (short*)(wsb + 40 * MiB);
        short* SB16 = (short*)(wsb + 46 * MiB);
        short* SBr0 = (short*)(wsb + 52 * MiB);
        short* SBr1 = (short*)(wsb + 58 * MiB);

        transpose_k<<<dim3(32, 32), dim3(32, 8), 0, stream>>>(Whh, TP);
        split_a<<<dim3(1, HH), 256, 0, stream>>>(Wxh, RS, RC, SBr0, RS, RC, HM);
        gemm_mx<<<dim3(16, 128), 256, 0, stream>>>(x, SBr0, rec, nuls, 0);
        split_a<<<dim3(1, HH), 256, 0, stream>>>(TP, RS, RC, SAP, RS, RC, HM);
        split_t<<<dim3(32, 32), dim3(32, 8), 0, stream>>>(TP, SBM);

        #define SQ64(SAi, SBi, Sot) \
            step_p64<<<dim3(16, 16), 256, 0, stream>>>(SAi, RS, RC, HM, SBi, \
                TP, RS, RC, 0, nulf, 0, 0, Sot, RS, RC, HM, 1024)
        SQ64(SAP, SBM, SA1);
        split_t<<<dim3(32, 32), dim3(32, 8), 0, stream>>>(TP, SBr0);
        SQ64(SA1, SBr0, SAP);
        split_t<<<dim3(32, 32), dim3(32, 8), 0, stream>>>(TP, SBr1);
        SQ64(SAP, SBr1, SA1);
        split_t<<<dim3(32, 32), dim3(32, 8), 0, stream>>>(TP, SB8);
        SQ64(SA1, SB8, SAP);
        split_t<<<dim3(32, 32), dim3(32, 8), 0, stream>>>(TP, SB16);

        split_a<<<dim3(1, 2048), 256, 0, stream>>>(rec, LH, CH8, SA0, RS, RC, PS2);
        for (int o = 1; o < C8; ++o) {
            short* Ain = (o & 1) ? SA0 : SA1;
            short* Sot = (o & 1) ? SA1 : SA0;
            step_p128<<<dim3(16, 16), 512, 0, stream>>>(Ain, RS, RC, PS2, SBM,
                rec + (size_t)o * HH, LH, CH8, 1, nulf, 0, 0,
                Sot, RS, RC, PS2, 2048);
        }
        #define SCAN(SRC, DST, T, SBpow) do { \
            int rows_ = (NC8 - (T)) * 32; \
            step_p128<<<dim3(16, (rows_ + 127) / 128), 512, 0, stream>>>( \
                SRC, RS, RC, PS2, SBpow, \
                rec + (size_t)((T) * C8 + C8 - 1) * HH, LH, CH8, 1, \
                nulf, 0, 0, DST + (size_t)(T) * RC, RS, RC, PS2, rows_); \
            copy_splits<<<(T) * 32, 256, 0, stream>>>(SRC, DST, PS2); \
        } while (0)
        #define SQI(SBi, SBo, last) do { \
            step_p64<<<dim3(16, 16), 256, 0, stream>>>(SAP, RS, RC, HM, SBi, \
                TP, RS, RC, 0, nulf, 0, 0, nuls, 0, 0, HM, 1024); \
            split_t<<<dim3(32, 32), dim3(32, 8), 0, stream>>>(TP, SBo); \
            if (!(last)) split_a<<<dim3(1, HH), 256, 0, stream>>>(TP, RS, RC, SAP, RS, RC, HM); \
        } while (0)
        SCAN(SA1, SA0, 1, SB8);
        SQI(SB16, SBr0, 0);
        SCAN(SA0, SA1, 2, SB16);
        SQI(SBr0, SBr1, 0);
        SCAN(SA1, SA0, 4, SBr0);
        SQI(SBr1, SBr0, 0);
        SCAN(SA0, SA1, 8, SBr1);
        SQI(SBr0, SBr1, 1);
        SCAN(SA1, SA0, 16, SBr0);
        SCAN(SA0, SA1, 32, SBr1);
        for (int o = 0; o < C8 - 1; ++o) {
            short* Ain = (o & 1) ? SA0 : SA1;
            short* Sot = (o & 1) ? SA1 : SA0;
            step_p128<<<dim3(16, 16), 512, 0, stream>>>(Ain, RS, RC, PS2, SBM,
                nulf, 0, 0, 0,
                rec + (size_t)(C8 + o) * HH, LH, CH8,
                (o == C8 - 2) ? nuls : Sot, RS, RC, PS2, 2016);
        }
        step_p<<<dim3(16, 1), 128, 0, stream>>>(SA1 + 63 * RC, RS, 0, PS2, SBM,
            outp, PB, 0, 0, nulf, 0, 0, SA0, RS, 0, PS2);
        step_p<<<dim3(16, 1), 128, 0, stream>>>(SA0, RS, 0, PS2, SBM,
            outp + HH, PB, 0, 0, nulf, 0, 0, SA0 + RC, RS, 0, PS2);
        tr_splits<<<dim3(32, 32, 3), dim3(32, 8), 0, stream>>>(SBM, SAP);
        SQ64(SAP, SBM, nuls);
        split_t<<<dim3(32, 32), dim3(32, 8), 0, stream>>>(TP, SBr0);
        step_p<<<dim3(16, 2), 128, 0, stream>>>(SA0, RS, RC, PS2, SBr0,
            outp + 2 * HH, PB, RS, 0, nulf, 0, 0,
            SA0 + 2 * RC, RS, RC, PS2);
        split_a<<<dim3(1, HH), 256, 0, stream>>>(TP, RS, RC, SAP, RS, RC, HM);
        SQ64(SAP, SBr0, nuls);
        split_t<<<dim3(32, 32), dim3(32, 8), 0, stream>>>(TP, SBr1);
        step_p<<<dim3(16, 4), 128, 0, stream>>>(SA0, RS, RC, PS2, SBr1,
            outp + 4 * HH, PB, RS, 0, nulf, 0, 0,
            SA0 + 4 * RC, RS, RC, PS2);
        step_p<<<dim3(16, 8), 128, 0, stream>>>(SA0, RS, RC, PS2, SB8,
            outp + 8 * HH, PB, RS, 0, nulf, 0, 0,
            SA0 + 8 * RC, RS, RC, PS2);
        step_p64<<<dim3(16, 8), 256, 0, stream>>>(SA0, RS, RC, PS2, SB16,
            outp + 16 * HH, PB, RS, 0, nulf, 0, 0,
            nuls, 0, 0, PS2, 512);
        #undef SQ64
        #undef SCAN
        #undef SQI

        ln_k<<<BB * PRED, 256, 0, stream>>>(outp, ln_w, ln_b);
    }
}